// Round 7
// baseline (205.815 us; speedup 1.0000x reference)
//
#include <hip/hip_runtime.h>

#define T_SEQ 2048
#define BATCH 2
#define HEADS 8
#define DHEAD 64
#define EMB   512

typedef __attribute__((ext_vector_type(8))) short short8;
typedef __attribute__((ext_vector_type(4))) float floatx4;
typedef __attribute__((ext_vector_type(8))) unsigned short ushort8;
typedef __attribute__((ext_vector_type(4))) unsigned short ushort4v;

// RNE convert (cold paths)
__device__ __forceinline__ unsigned short f2b(float f) {
    union { float f; unsigned u; } v; v.f = f;
    unsigned r = v.u + 0x7fffu + ((v.u >> 16) & 1u);
    return (unsigned short)(r >> 16);
}
// 1-op truncating convert (hot paths)
__device__ __forceinline__ unsigned short f2bt(float f) {
    union { float f; unsigned u; } v; v.f = f;
    return (unsigned short)(v.u >> 16);
}
__device__ __forceinline__ float b2f(unsigned short s) {
    union { unsigned u; float f; } v; v.u = ((unsigned)s) << 16; return v.f;
}
__device__ __forceinline__ short8 ld_frag(const unsigned short* p) {
    ushort4v lo = *(const ushort4v*)p;
    ushort4v hi = *(const ushort4v*)(p + 4);
    short8 r;
    r[0] = lo[0]; r[1] = lo[1]; r[2] = lo[2]; r[3] = lo[3];
    r[4] = hi[0]; r[5] = hi[1]; r[6] = hi[2]; r[7] = hi[3];
    return r;
}
__device__ __forceinline__ void st8(unsigned short* p, ushort8 v) {
    ushort4v lo = { v[0], v[1], v[2], v[3] };
    ushort4v hi = { v[4], v[5], v[6], v[7] };
    *(ushort4v*)p = lo;
    *(ushort4v*)(p + 4) = hi;
}
// fp32 pair -> bf16x8 (RNE, matches old cvt_all numerics exactly)
__device__ __forceinline__ ushort8 cv8(const float4 lo, const float4 hi) {
    ushort8 u;
    u[0] = f2b(lo.x); u[1] = f2b(lo.y); u[2] = f2b(lo.z); u[3] = f2b(lo.w);
    u[4] = f2b(hi.x); u[5] = f2b(hi.y); u[6] = f2b(hi.z); u[7] = f2b(hi.w);
    return u;
}
#define MFMA16(a, b, c) __builtin_amdgcn_mfma_f32_16x16x32_bf16(a, b, c, 0, 0, 0)

// ---------------------------------------------------------------------------
// Fused QKV + pos projection GEMM (448 blocks), 128x128 tiles, BK=64,
// double-buffered LDS + register prefetch: 1 barrier per k-iter (8 total).
// R7: inputs are the ORIGINAL fp32 tensors; conversion to bf16 happens
// in-staging (float4 fetch -> f2b RNE -> st8). cvt_all kernel deleted.
// blocks 0..383: QKV; bn<1024 -> q_s/k_s scatter; bn>=1024 -> vT via LDS
// transpose. blocks 384..447: pos -> r bf16 [R,E].
// LDS: As0@0 Bs0@8704 As1@17408 Bs1@26112 (each 128x68) = 69,632 B -> 2/CU.
// ---------------------------------------------------------------------------
__global__ __launch_bounds__(256)
void gemm_qkv_pos(const float* __restrict__ inF, const float* __restrict__ w_inF,
                  const float* __restrict__ b_in,
                  const float* __restrict__ posF, const float* __restrict__ w_posF,
                  const float* __restrict__ b_pos,
                  unsigned short* __restrict__ q_s, unsigned short* __restrict__ k_s,
                  unsigned short* __restrict__ vT, unsigned short* __restrict__ r_b)
{
    __shared__ unsigned short shmem[34816];
    unsigned short* tb = shmem;                 // 128x131 transpose buf (aliases buf0)

    const int id = blockIdx.x;
    const bool isPos = (id >= 384);
    const int bx = isPos ? ((id - 384) & 3) : (id % 12);
    const int by = isPos ? ((id - 384) >> 2) : (id / 12);
    const float* A = isPos ? posF : inF;
    const float* B = isPos ? w_posF : w_inF;
    const float* bias = isPos ? b_pos : b_in;

    const int bm  = by * 128;
    const int bn  = bx * 128;
    const int tid = threadIdx.x;
    const int lane = tid & 63, w = tid >> 6;
    const int m16 = lane & 15, quad = lane >> 4;
    const int wm = (w & 1) * 64, wn = (w >> 1) * 64;
    const int srow = tid >> 1, scol = (tid & 1) * 32;

    floatx4 acc[4][4];
    #pragma unroll
    for (int i = 0; i < 4; ++i)
        #pragma unroll
        for (int j = 0; j < 4; ++j) acc[i][j] = (floatx4){0.f, 0.f, 0.f, 0.f};

    float4 fa[8], fb[8];
    auto fetch = [&](int k0) {
        const float* Arow = A + (size_t)(bm + srow) * 512 + k0 + scol;
        const float* Brow = B + (size_t)(bn + srow) * 512 + k0 + scol;
        #pragma unroll
        for (int c = 0; c < 8; ++c) fa[c] = ((const float4*)Arow)[c];
        #pragma unroll
        for (int c = 0; c < 8; ++c) fb[c] = ((const float4*)Brow)[c];
    };
    auto store_stage = [&](int q) {
        unsigned short* As = shmem + q * 17408;
        unsigned short* Bs = shmem + q * 17408 + 8704;
        #pragma unroll
        for (int c = 0; c < 4; ++c) st8(&As[srow * 68 + scol + c * 8], cv8(fa[2 * c], fa[2 * c + 1]));
        #pragma unroll
        for (int c = 0; c < 4; ++c) st8(&Bs[srow * 68 + scol + c * 8], cv8(fb[2 * c], fb[2 * c + 1]));
    };

    fetch(0);
    store_stage(0);
    __syncthreads();

    for (int kt = 0; kt < 8; ++kt) {
        const int p = kt & 1;
        unsigned short* As = shmem + p * 17408;
        unsigned short* Bs = shmem + p * 17408 + 8704;
        if (kt + 1 < 8) fetch((kt + 1) * 64);
        #pragma unroll
        for (int ks = 0; ks < 2; ++ks) {
            short8 af[4], bf[4];
            #pragma unroll
            for (int f = 0; f < 4; ++f) {
                af[f] = ld_frag(&As[(wm + f * 16 + m16) * 68 + ks * 32 + quad * 8]);
                bf[f] = ld_frag(&Bs[(wn + f * 16 + m16) * 68 + ks * 32 + quad * 8]);
            }
            #pragma unroll
            for (int fm = 0; fm < 4; ++fm)
                #pragma unroll
                for (int fn = 0; fn < 4; ++fn)
                    acc[fm][fn] = MFMA16(af[fm], bf[fn], acc[fm][fn]);
        }
        if (kt + 1 < 8) store_stage(1 - p);
        __syncthreads();
    }

    if (isPos) {
        #pragma unroll
        for (int fn = 0; fn < 4; ++fn) {
            const int n = bn + wn + fn * 16 + m16;
            const float bv = bias[n];
            #pragma unroll
            for (int fm = 0; fm < 4; ++fm)
                #pragma unroll
                for (int rgi = 0; rgi < 4; ++rgi) {
                    const int m = bm + wm + fm * 16 + quad * 4 + rgi;
                    r_b[(size_t)m * EMB + n] = f2b(acc[fm][fn][rgi] + bv);
                }
        }
    } else if (bn < 1024) {
        #pragma unroll
        for (int fn = 0; fn < 4; ++fn) {
            const int n = bn + wn + fn * 16 + m16;
            const float bv = bias[n];
            const int reg = n >> 9, c = n & 511, h = c >> 6, dd = c & 63;
            unsigned short* dst = reg == 0 ? q_s : k_s;
            #pragma unroll
            for (int fm = 0; fm < 4; ++fm)
                #pragma unroll
                for (int rgi = 0; rgi < 4; ++rgi) {
                    const int m = bm + wm + fm * 16 + quad * 4 + rgi;
                    const int t = m >> 1, b = m & 1;
                    dst[((size_t)(b * HEADS + h) * T_SEQ + t) * DHEAD + dd] = f2b(acc[fm][fn][rgi] + bv);
                }
        }
    } else {
        #pragma unroll
        for (int fn = 0; fn < 4; ++fn) {
            const int nl = wn + fn * 16 + m16;
            const float bv = bias[bn + nl];
            #pragma unroll
            for (int fm = 0; fm < 4; ++fm)
                #pragma unroll
                for (int rgi = 0; rgi < 4; ++rgi) {
                    const int ml = wm + fm * 16 + quad * 4 + rgi;
                    tb[nl * 131 + ml] = f2b(acc[fm][fn][rgi] + bv);
                }
        }
        __syncthreads();
        const int t0g = bm >> 1;
        for (int s2 = tid; s2 < 2048; s2 += 256) {
            const int nl = s2 >> 4;
            const int bsel = (s2 >> 3) & 1;
            const int j = s2 & 7;
            ushort8 o;
            #pragma unroll
            for (int k = 0; k < 8; ++k)
                o[k] = tb[nl * 131 + ((j * 8 + k) * 2 + bsel)];
            const int c = bn + nl - 1024, h = c >> 6, dd = c & 63;
            *(ushort8*)(vT + ((size_t)(bsel * HEADS + h) * DHEAD + dd) * T_SEQ + t0g + j * 8) = o;
        }
    }
}

// ---------------------------------------------------------------------------
// Output GEMM: ctx bf16 [4096,512] x w_out (fp32, converted in-staging)
// -> fp32 out. 64x64 tiles, grid (8,64) = 512 blocks, BK=64, dbuf.
// LDS 34,816 B.
// ---------------------------------------------------------------------------
__global__ __launch_bounds__(256)
void gemm_out(const unsigned short* __restrict__ A, const float* __restrict__ B,
              const float* __restrict__ bias, float* __restrict__ out)
{
    __shared__ unsigned short shmem[17408];
    const int bm  = blockIdx.y * 64;
    const int bn  = blockIdx.x * 64;
    const int tid = threadIdx.x;
    const int lane = tid & 63, w = tid >> 6;
    const int m16 = lane & 15, quad = lane >> 4;
    const int wm = (w & 1) * 32, wn = (w >> 1) * 32;
    const int srow = tid >> 2, scol = (tid & 3) * 16;

    floatx4 acc[2][2];
    #pragma unroll
    for (int i = 0; i < 2; ++i)
        #pragma unroll
        for (int j = 0; j < 2; ++j) acc[i][j] = (floatx4){0.f, 0.f, 0.f, 0.f};

    ushort8 ar[2];
    float4 fb[4];
    auto fetch = [&](int k0) {
        ar[0] = *(const ushort8*)(A + (size_t)(bm + srow) * 512 + k0 + scol);
        ar[1] = *(const ushort8*)(A + (size_t)(bm + srow) * 512 + k0 + scol + 8);
        const float* Brow = B + (size_t)(bn + srow) * 512 + k0 + scol;
        #pragma unroll
        for (int c = 0; c < 4; ++c) fb[c] = ((const float4*)Brow)[c];
    };
    auto store_stage = [&](int q) {
        unsigned short* As = shmem + q * 8704;
        unsigned short* Bs = shmem + q * 8704 + 4352;
        st8(&As[srow * 68 + scol + 0], ar[0]);
        st8(&As[srow * 68 + scol + 8], ar[1]);
        st8(&Bs[srow * 68 + scol + 0], cv8(fb[0], fb[1]));
        st8(&Bs[srow * 68 + scol + 8], cv8(fb[2], fb[3]));
    };

    fetch(0);
    store_stage(0);
    __syncthreads();

    for (int kt = 0; kt < 8; ++kt) {
        const int p = kt & 1;
        unsigned short* As = shmem + p * 8704;
        unsigned short* Bs = shmem + p * 8704 + 4352;
        if (kt + 1 < 8) fetch((kt + 1) * 64);
        #pragma unroll
        for (int ks = 0; ks < 2; ++ks) {
            short8 af[2], bf[2];
            #pragma unroll
            for (int f = 0; f < 2; ++f) {
                af[f] = ld_frag(&As[(wm + f * 16 + m16) * 68 + ks * 32 + quad * 8]);
                bf[f] = ld_frag(&Bs[(wn + f * 16 + m16) * 68 + ks * 32 + quad * 8]);
            }
            #pragma unroll
            for (int fm = 0; fm < 2; ++fm)
                #pragma unroll
                for (int fn = 0; fn < 2; ++fn)
                    acc[fm][fn] = MFMA16(af[fm], bf[fn], acc[fm][fn]);
        }
        if (kt + 1 < 8) store_stage(1 - p);
        __syncthreads();
    }

    #pragma unroll
    for (int fn = 0; fn < 2; ++fn) {
        const int n = bn + wn + fn * 16 + m16;
        const float bv = bias[n];
        #pragma unroll
        for (int fm = 0; fm < 2; ++fm)
            #pragma unroll
            for (int rgi = 0; rgi < 4; ++rgi) {
                const int m = bm + wm + fm * 16 + quad * 4 + rgi;
                out[(size_t)m * EMB + n] = acc[fm][fn][rgi] + bv;
            }
    }
}

// ---------------------------------------------------------------------------
// Fused MFMA attention — R1 proven version (89.8 us), barrier-reduced.
//   bd[t][s] = QR[t][T-1-t+s] (s<=t) | 0 (s==t+1) | QR[t+1][s-t-2] (s>=t+2)
// Wave-privacy facts (rows ibase+rgi = 16w+quad*4+rgi): ring rows and pbuf
// rows are wave-private -> no barrier between qr_half/ring adds, nor around
// the P round-trip. ONE barrier per s-tile at tile end. Diagonal Bd1-Bd3.
// LDS (u16): k@0 (2x4352) v@8704 (2x4352) rp@17408 (2x4352) pbuf@26112
// (4352) ring@30464 (64x133 = 8512). 77,952 B -> 2 blocks/CU.
// ---------------------------------------------------------------------------
__global__ __launch_bounds__(256)
void attn_mfma(const unsigned short* __restrict__ qg_, const unsigned short* __restrict__ kg_,
               const unsigned short* __restrict__ vtg_, const unsigned short* __restrict__ rg_,
               const float* __restrict__ rwb, const float* __restrict__ rrb,
               unsigned short* __restrict__ ctx)
{
    const int T   = T_SEQ;
    const int tb  = blockIdx.x;
    const int t0  = tb * 64;
    const int bh  = blockIdx.y;
    const int h   = bh & 7;
    const int b   = bh >> 3;
    const int tid = threadIdx.x;
    const int lane = tid & 63;
    const int w    = tid >> 6;
    const int m16  = lane & 15;
    const int quad = lane >> 4;
    const int ibase = 16 * w + quad * 4;

    __shared__ unsigned short lds[38976];
    unsigned short* pbuf  = lds + 26112;
    unsigned short* ring  = lds + 30464;
    unsigned short* qrw_s = lds;
    unsigned short* qrr_s = lds + 8704;

    const unsigned short* qg  = qg_  + ((size_t)bh * T + t0) * DHEAD;
    const unsigned short* kg  = kg_  + (size_t)bh * T * DHEAD;
    const unsigned short* vtg = vtg_ + (size_t)bh * DHEAD * T;
    const unsigned short* rg  = rg_  + h * DHEAD;

    const float QSCALE = 0.125f * 1.44269504089f;
    for (int idx = tid; idx < 65 * 16; idx += 256) {
        const int row = idx >> 4, c = (idx & 15) << 2;
        ushort4v qv = {0, 0, 0, 0};
        if (t0 + row < T) qv = *(const ushort4v*)(qg + row * DHEAD + c);
        const float4 rr = *(const float4*)(rrb + h * DHEAD + c);
        qrr_s[row * 68 + c + 0] = f2b((b2f(qv[0]) + rr.x) * QSCALE);
        qrr_s[row * 68 + c + 1] = f2b((b2f(qv[1]) + rr.y) * QSCALE);
        qrr_s[row * 68 + c + 2] = f2b((b2f(qv[2]) + rr.z) * QSCALE);
        qrr_s[row * 68 + c + 3] = f2b((b2f(qv[3]) + rr.w) * QSCALE);
        if (row < 64) {
            const float4 rw = *(const float4*)(rwb + h * DHEAD + c);
            qrw_s[row * 68 + c + 0] = f2b((b2f(qv[0]) + rw.x) * QSCALE);
            qrw_s[row * 68 + c + 1] = f2b((b2f(qv[1]) + rw.y) * QSCALE);
            qrw_s[row * 68 + c + 2] = f2b((b2f(qv[2]) + rw.z) * QSCALE);
            qrw_s[row * 68 + c + 3] = f2b((b2f(qv[3]) + rw.w) * QSCALE);
        }
    }
    __syncthreads();

    short8 a_ac[2], a_qrl[2], a_qru[2];
    {
        const unsigned short* p0 = &qrw_s[(16 * w + m16) * 68 + quad * 8];
        a_ac[0]  = ld_frag(p0);  a_ac[1]  = ld_frag(p0 + 32);
        const unsigned short* p1 = &qrr_s[(16 * w + m16) * 68 + quad * 8];
        a_qrl[0] = ld_frag(p1);  a_qrl[1] = ld_frag(p1 + 32);
        const unsigned short* p2 = &qrr_s[(16 * w + 1 + m16) * 68 + quad * 8];
        a_qru[0] = ld_frag(p2);  a_qru[1] = ld_frag(p2 + 32);
    }

    const int srow0 = tid >> 3,          scol0 = (tid & 7) * 8;
    const int srow1 = (tid + 256) >> 3,  scol1 = (tid & 7) * 8;

    ushort8 kr[2], vr[2], rr8[2];
    auto prefetch = [&](int s0n) {
        const bool ln = (s0n <= t0);
        const int jb = (ln ? (s0n + T - t0 - 64) : (s0n - t0 - 65)) + 64;
        int j0 = jb + srow0; j0 = j0 < 0 ? 0 : (j0 > T - 1 ? T - 1 : j0);
        int j1 = jb + srow1; j1 = j1 < 0 ? 0 : (j1 > T - 1 ? T - 1 : j1);
        kr[0]  = *(const ushort8*)(kg + (size_t)(s0n + srow0) * DHEAD + scol0);
        kr[1]  = *(const ushort8*)(kg + (size_t)(s0n + srow1) * DHEAD + scol1);
        vr[0]  = *(const ushort8*)(vtg + (size_t)srow0 * T + s0n + scol0);
        vr[1]  = *(const ushort8*)(vtg + (size_t)srow1 * T + s0n + scol1);
        rr8[0] = *(const ushort8*)(rg + (size_t)j0 * EMB + scol0);
        rr8[1] = *(const ushort8*)(rg + (size_t)j1 * EMB + scol1);
    };
    auto store_bufs = [&](int q) {
        unsigned short* kb = lds + q * 4352;
        unsigned short* vb = lds + 8704 + q * 4352;
        unsigned short* rb = lds + 17408 + q * 4352;
        st8(&kb[srow0 * 68 + scol0], kr[0]);
        st8(&kb[srow1 * 68 + scol1], kr[1]);
        st8(&vb[srow0 * 68 + scol0], vr[0]);
        st8(&vb[srow1 * 68 + scol1], vr[1]);
        st8(&rb[srow0 * 68 + scol0], rr8[0]);
        st8(&rb[srow1 * 68 + scol1], rr8[1]);
    };
    auto stage_to = [&](unsigned short* dstb, int jbase) {
        #pragma unroll
        for (int idx = tid; idx < 512; idx += 256) {
            const int row = idx >> 3, c = (idx & 7) * 8;
            int j = jbase + row; j = j < 0 ? 0 : (j > T - 1 ? T - 1 : j);
            st8(&dstb[row * 68 + c], *(const ushort8*)(rg + (size_t)j * EMB + c));
        }
    };
    auto qr_half = [&](const unsigned short* rsb, const short8* aq, int slotbase) {
        #pragma unroll
        for (int cc = 0; cc < 4; ++cc) {
            floatx4 q4 = (floatx4){0.f, 0.f, 0.f, 0.f};
            #pragma unroll
            for (int ks = 0; ks < 2; ++ks) {
                short8 bfr = ld_frag(&rsb[(16 * cc + m16) * 68 + ks * 32 + quad * 8]);
                q4 = MFMA16(aq[ks], bfr, q4);
            }
            #pragma unroll
            for (int rgi = 0; rgi < 4; ++rgi)
                ring[(ibase + rgi) * 133 + slotbase + 16 * cc + m16] = f2bt(q4[rgi]);
        }
    };

    floatx4 O[4];
    float lrun[4];
    #pragma unroll
    for (int ct = 0; ct < 4; ++ct) O[ct] = (floatx4){0.f, 0.f, 0.f, 0.f};
    #pragma unroll
    for (int rgi = 0; rgi < 4; ++rgi) lrun[rgi] = 0.f;

    {
        stage_to(lds + 17408 + 4352, T - t0 - 64);
        prefetch(0);
        __syncthreads();
        qr_half(lds + 17408 + 4352, a_qrl, 0);
        store_bufs(0);
        __syncthreads();
    }

    for (int na = 0; na < T / 64; ++na) {
        const int s0 = na * 64;
        const int p = na & 1;
        unsigned short* kb = lds + p * 4352;
        unsigned short* vb = lds + 8704 + p * 4352;
        unsigned short* rp = lds + 17408 + p * 4352;
        const bool lower = (s0 <= t0);
        const int nph    = lower ? (s0 >> 6) : ((s0 - t0) >> 6);
        const int rbase  = (nph & 1) * 64;
        const int wbase  = 64 - rbase;
        const bool hasNext = (na + 1 < T / 64);

        floatx4 acf[4];
        __builtin_amdgcn_s_setprio(1);
        #pragma unroll
        for (int ct = 0; ct < 4; ++ct) {
            acf[ct] = (floatx4){0.f, 0.f, 0.f, 0.f};
            #pragma unroll
            for (int ks = 0; ks < 2; ++ks) {
                short8 bfr = ld_frag(&kb[(16 * ct + m16) * 68 + ks * 32 + quad * 8]);
                acf[ct] = MFMA16(a_ac[ks], bfr, acf[ct]);
            }
        }
        __builtin_amdgcn_s_setprio(0);
        if (hasNext) prefetch(s0 + 64);
        qr_half(rp, lower ? a_qrl : a_qru, wbase);
        // no barrier: ring rows are wave-private, DS ops in-order per wave

        if (s0 != t0) {
            #pragma unroll
            for (int ct = 0; ct < 4; ++ct) {
                #pragma unroll
                for (int rgi = 0; rgi < 4; ++rgi) {
                    const int i = ibase + rgi;
                    const int slot = ((63 - i + 16 * ct + m16) + rbase) & 127;
                    acf[ct][rgi] += b2f(ring[i * 133 + slot]);
                }
            }
            if (s0 == t0 + 64 && lane == 48 && w == 3)
                acf[0][3] -= b2f(ring[63 * 133 + (rbase & 127)]);
        } else {
            #pragma unroll
            for (int ct = 0; ct < 4; ++ct) {
                #pragma unroll
                for (int rgi = 0; rgi < 4; ++rgi) {
                    const int i = ibase + rgi, u = 16 * ct + m16;
                    if (u <= i) acf[ct][rgi] += b2f(ring[i * 133 + (((63 - i + u) + rbase) & 127)]);
                }
            }
            unsigned short* rpo = lds + 17408 + (1 - p) * 4352;
            __syncthreads();                   // Bd1
            stage_to(rpo, -1);
            __syncthreads();                   // Bd2
            qr_half(rpo, a_qru, 64);
            __syncthreads();                   // Bd3 (also guards store_bufs(1-p) below)
            #pragma unroll
            for (int ct = 0; ct < 4; ++ct) {
                #pragma unroll
                for (int rgi = 0; rgi < 4; ++rgi) {
                    const int i = ibase + rgi, u = 16 * ct + m16;
                    if (u >= i + 2) acf[ct][rgi] += b2f(ring[i * 133 + 63 - i + u]);
                }
            }
        }

        #pragma unroll
        for (int rgi = 0; rgi < 4; ++rgi) {
            #pragma unroll
            for (int ct = 0; ct < 4; ++ct) {
                const float pv = exp2f(acf[ct][rgi]);
                acf[ct][rgi] = pv;
                lrun[rgi] += pv;
            }
        }
        // P -> dedicated pbuf (same-wave cross-lane exchange, no barrier)
        #pragma unroll
        for (int ct = 0; ct < 4; ++ct)
            #pragma unroll
            for (int rgi = 0; rgi < 4; ++rgi)
                pbuf[(ibase + rgi) * 68 + 16 * ct + m16] = f2bt(acf[ct][rgi]);

        short8 ap[2];
        {
            const unsigned short* pp = &pbuf[(16 * w + m16) * 68 + quad * 8];
            ap[0] = ld_frag(pp); ap[1] = ld_frag(pp + 32);
        }
        __builtin_amdgcn_s_setprio(1);
        #pragma unroll
        for (int ct = 0; ct < 4; ++ct) {
            #pragma unroll
            for (int ks = 0; ks < 2; ++ks) {
                short8 bfr = ld_frag(&vb[(16 * ct + m16) * 68 + ks * 32 + quad * 8]);
                O[ct] = MFMA16(ap[ks], bfr, O[ct]);
            }
        }
        __builtin_amdgcn_s_setprio(0);
        if (hasNext) store_bufs(1 - p);
        __syncthreads();                       // single tile-boundary barrier
    }

    #pragma unroll
    for (int rgi = 0; rgi < 4; ++rgi) {
        float l = lrun[rgi];
        #pragma unroll
        for (int off = 1; off < 16; off <<= 1)
            l += __shfl_xor(l, off);
        const float inv = 1.f / l;
        const int t = t0 + ibase + rgi;
        #pragma unroll
        for (int ct = 0; ct < 4; ++ct)
            ctx[((size_t)t * BATCH + b) * EMB + h * DHEAD + 16 * ct + m16] = f2bt(O[ct][rgi] * inv);
    }
}

// ---------------------------------------------------------------------------
// Workspace (ushort offsets) — only attention intermediates now:
//   6553600 q_s | 8650752 k_s | 10747904 vT | 12845056 r_b | 13893632 ctx_b
// (offsets kept from previous layout; earlier regions unused)
// ---------------------------------------------------------------------------
extern "C" void kernel_launch(void* const* d_in, const int* in_sizes, int n_in,
                              void* d_out, int out_size, void* d_ws, size_t ws_size,
                              hipStream_t stream)
{
    const float* input = (const float*)d_in[0];
    const float* pos   = (const float*)d_in[1];
    const float* w_in  = (const float*)d_in[2];
    const float* w_out = (const float*)d_in[3];
    const float* w_pos = (const float*)d_in[4];
    const float* b_in  = (const float*)d_in[5];
    const float* b_out = (const float*)d_in[6];
    const float* b_pos = (const float*)d_in[7];
    const float* rwb   = (const float*)d_in[8];
    const float* rrb   = (const float*)d_in[9];

    unsigned short* ws     = (unsigned short*)d_ws;
    unsigned short* q_s    = ws + 6553600;
    unsigned short* k_s    = ws + 8650752;
    unsigned short* vT     = ws + 10747904;
    unsigned short* r_b    = ws + 12845056;
    unsigned short* ctx_b  = ws + 13893632;

    gemm_qkv_pos<<<448, 256, 0, stream>>>(input, w_in, b_in, pos, w_pos, b_pos,
                                          q_s, k_s, vT, r_b);
    attn_mfma<<<dim3(32, 16), 256, 0, stream>>>(q_s, k_s, vT, r_b, rwb, rrb, ctx_b);
    gemm_out<<<dim3(8, 64), 256, 0, stream>>>(ctx_b, w_out, b_out, (float*)d_out);
}

// Round 8
// 190.981 us; speedup vs baseline: 1.0777x; 1.0777x over previous
//
#include <hip/hip_runtime.h>

#define T_SEQ 2048
#define BATCH 2
#define HEADS 8
#define DHEAD 64
#define EMB   512

typedef __attribute__((ext_vector_type(8))) short short8;
typedef __attribute__((ext_vector_type(4))) float floatx4;
typedef __attribute__((ext_vector_type(8))) unsigned short ushort8;
typedef __attribute__((ext_vector_type(4))) unsigned short ushort4v;

// RNE convert (cold paths)
__device__ __forceinline__ unsigned short f2b(float f) {
    union { float f; unsigned u; } v; v.f = f;
    unsigned r = v.u + 0x7fffu + ((v.u >> 16) & 1u);
    return (unsigned short)(r >> 16);
}
// 1-op truncating convert (hot paths)
__device__ __forceinline__ unsigned short f2bt(float f) {
    union { float f; unsigned u; } v; v.f = f;
    return (unsigned short)(v.u >> 16);
}
__device__ __forceinline__ float b2f(unsigned short s) {
    union { unsigned u; float f; } v; v.u = ((unsigned)s) << 16; return v.f;
}
__device__ __forceinline__ short8 ld_frag(const unsigned short* p) {
    ushort4v lo = *(const ushort4v*)p;
    ushort4v hi = *(const ushort4v*)(p + 4);
    short8 r;
    r[0] = lo[0]; r[1] = lo[1]; r[2] = lo[2]; r[3] = lo[3];
    r[4] = hi[0]; r[5] = hi[1]; r[6] = hi[2]; r[7] = hi[3];
    return r;
}
__device__ __forceinline__ void st8(unsigned short* p, ushort8 v) {
    ushort4v lo = { v[0], v[1], v[2], v[3] };
    ushort4v hi = { v[4], v[5], v[6], v[7] };
    *(ushort4v*)p = lo;
    *(ushort4v*)(p + 4) = hi;
}
#define MFMA16(a, b, c) __builtin_amdgcn_mfma_f32_16x16x32_bf16(a, b, c, 0, 0, 0)

// ---------------------------------------------------------------------------
// One-shot fp32 -> bf16 conversion of all 5 tensors. (R7 showed folding this
// into the GEMMs doubles their global traffic and loses ~19us -- keep it.)
// ---------------------------------------------------------------------------
__global__ __launch_bounds__(256)
void cvt_all(const float* __restrict__ s0, const float* __restrict__ s1,
             const float* __restrict__ s2, const float* __restrict__ s3,
             const float* __restrict__ s4,
             unsigned short* __restrict__ d0, unsigned short* __restrict__ d1,
             unsigned short* __restrict__ d2, unsigned short* __restrict__ d3,
             unsigned short* __restrict__ d4)
{
    const int i = blockIdx.x * 256 + threadIdx.x;
    const float* s; unsigned short* d; int off;
    if      (i <  524288) { s = s0; d = d0; off = i; }
    else if (i <  786432) { s = s1; d = d1; off = i -  524288; }
    else if (i <  983040) { s = s2; d = d2; off = i -  786432; }
    else if (i < 1048576) { s = s3; d = d3; off = i -  983040; }
    else if (i < 1114112) { s = s4; d = d4; off = i - 1048576; }
    else return;
    const float4 v = ((const float4*)s)[off];
    ushort4v o = { f2b(v.x), f2b(v.y), f2b(v.z), f2b(v.w) };
    ((ushort4v*)d)[off] = o;
}

// ---------------------------------------------------------------------------
// Fused QKV + pos projection GEMM.
// R8: 64x128 tiles -> grid 64x12 (QKV) + 32x4 (pos) = 896 blocks
// = 3.5 blocks/CU, 14 waves/CU (was 448 blocks = 1.75/CU, latency-bound).
// Single-buffered LDS: As 64x68 @0 + Bs 128x68 @4352 = 13,056 ush = 26,112 B
// (all 896 blocks resident). Register prefetch keeps global latency hidden;
// 2 barriers/k-iter covered by 3.5 co-resident blocks.
// 4 waves 2Mx2N: wave out 32x64 = acc[2][4].
// blocks bn<1024: q_s/k_s scatter; bn>=1024: vT via 128x67 LDS transpose.
// pos blocks: r bf16 [R,E].
// ---------------------------------------------------------------------------
__global__ __launch_bounds__(256)
void gemm_qkv_pos(const unsigned short* __restrict__ inb, const unsigned short* __restrict__ w_inb,
                  const float* __restrict__ b_in,
                  const unsigned short* __restrict__ posb, const unsigned short* __restrict__ w_posb,
                  const float* __restrict__ b_pos,
                  unsigned short* __restrict__ q_s, unsigned short* __restrict__ k_s,
                  unsigned short* __restrict__ vT, unsigned short* __restrict__ r_b)
{
    __shared__ unsigned short shmem[13056];
    unsigned short* As = shmem;                 // 64x68
    unsigned short* Bs = shmem + 4352;          // 128x68
    unsigned short* tb = shmem;                 // 128x67 transpose buf alias (8576 ush)

    const int id = blockIdx.x;
    const bool isPos = (id >= 768);
    const int bx = isPos ? ((id - 768) & 3) : (id % 12);
    const int by = isPos ? ((id - 768) >> 2) : (id / 12);
    const unsigned short* A = isPos ? posb : inb;
    const unsigned short* B = isPos ? w_posb : w_inb;
    const float* bias = isPos ? b_pos : b_in;

    const int bm  = by * 64;
    const int bn  = bx * 128;
    const int tid = threadIdx.x;
    const int lane = tid & 63, w = tid >> 6;
    const int m16 = lane & 15, quad = lane >> 4;
    const int wm = (w & 1) * 32, wn = (w >> 1) * 64;
    const int srA = tid >> 2, scA = (tid & 3) * 16;   // A: 64 rows x 64 cols
    const int srB = tid >> 1, scB = (tid & 1) * 32;   // B: 128 rows x 64 cols

    floatx4 acc[2][4];
    #pragma unroll
    for (int i = 0; i < 2; ++i)
        #pragma unroll
        for (int j = 0; j < 4; ++j) acc[i][j] = (floatx4){0.f, 0.f, 0.f, 0.f};

    ushort8 ar[2], br[4];
    auto fetch = [&](int k0) {
        ar[0] = *(const ushort8*)(A + (size_t)(bm + srA) * 512 + k0 + scA);
        ar[1] = *(const ushort8*)(A + (size_t)(bm + srA) * 512 + k0 + scA + 8);
        br[0] = *(const ushort8*)(B + (size_t)(bn + srB) * 512 + k0 + scB);
        br[1] = *(const ushort8*)(B + (size_t)(bn + srB) * 512 + k0 + scB + 8);
        br[2] = *(const ushort8*)(B + (size_t)(bn + srB) * 512 + k0 + scB + 16);
        br[3] = *(const ushort8*)(B + (size_t)(bn + srB) * 512 + k0 + scB + 24);
    };
    auto store_stage = [&]() {
        st8(&As[srA * 68 + scA + 0], ar[0]);
        st8(&As[srA * 68 + scA + 8], ar[1]);
        st8(&Bs[srB * 68 + scB +  0], br[0]);
        st8(&Bs[srB * 68 + scB +  8], br[1]);
        st8(&Bs[srB * 68 + scB + 16], br[2]);
        st8(&Bs[srB * 68 + scB + 24], br[3]);
    };

    fetch(0);
    store_stage();
    __syncthreads();

    for (int kt = 0; kt < 8; ++kt) {
        if (kt + 1 < 8) fetch((kt + 1) * 64);
        #pragma unroll
        for (int ks = 0; ks < 2; ++ks) {
            short8 af[2], bf[4];
            #pragma unroll
            for (int f = 0; f < 2; ++f)
                af[f] = ld_frag(&As[(wm + f * 16 + m16) * 68 + ks * 32 + quad * 8]);
            #pragma unroll
            for (int f = 0; f < 4; ++f)
                bf[f] = ld_frag(&Bs[(wn + f * 16 + m16) * 68 + ks * 32 + quad * 8]);
            #pragma unroll
            for (int fm = 0; fm < 2; ++fm)
                #pragma unroll
                for (int fn = 0; fn < 4; ++fn)
                    acc[fm][fn] = MFMA16(af[fm], bf[fn], acc[fm][fn]);
        }
        __syncthreads();                  // all reads of As/Bs done
        if (kt + 1 < 8) {
            store_stage();
            __syncthreads();              // next tile visible
        }
    }

    if (isPos) {
        #pragma unroll
        for (int fn = 0; fn < 4; ++fn) {
            const int n = bn + wn + fn * 16 + m16;
            const float bv = bias[n];
            #pragma unroll
            for (int fm = 0; fm < 2; ++fm)
                #pragma unroll
                for (int rgi = 0; rgi < 4; ++rgi) {
                    const int m = bm + wm + fm * 16 + quad * 4 + rgi;
                    r_b[(size_t)m * EMB + n] = f2b(acc[fm][fn][rgi] + bv);
                }
        }
    } else if (bn < 1024) {
        #pragma unroll
        for (int fn = 0; fn < 4; ++fn) {
            const int n = bn + wn + fn * 16 + m16;
            const float bv = bias[n];
            const int reg = n >> 9, c = n & 511, h = c >> 6, dd = c & 63;
            unsigned short* dst = reg == 0 ? q_s : k_s;
            #pragma unroll
            for (int fm = 0; fm < 2; ++fm)
                #pragma unroll
                for (int rgi = 0; rgi < 4; ++rgi) {
                    const int m = bm + wm + fm * 16 + quad * 4 + rgi;
                    const int t = m >> 1, b = m & 1;
                    dst[((size_t)(b * HEADS + h) * T_SEQ + t) * DHEAD + dd] = f2b(acc[fm][fn][rgi] + bv);
                }
        }
    } else {
        // vT transpose: tb 128x67 (aliases As/Bs -- dead after last barrier)
        #pragma unroll
        for (int fn = 0; fn < 4; ++fn) {
            const int nl = wn + fn * 16 + m16;
            const float bv = bias[bn + nl];
            #pragma unroll
            for (int fm = 0; fm < 2; ++fm)
                #pragma unroll
                for (int rgi = 0; rgi < 4; ++rgi) {
                    const int ml = wm + fm * 16 + quad * 4 + rgi;
                    tb[nl * 67 + ml] = f2b(acc[fm][fn][rgi] + bv);
                }
        }
        __syncthreads();
        const int t0g = bm >> 1;
        for (int s2 = tid; s2 < 1024; s2 += 256) {
            const int nl = s2 >> 3;            // [0,128)
            const int bsel = (s2 >> 2) & 1;
            const int j = s2 & 3;              // [0,4): 8 t-values each
            ushort8 o;
            #pragma unroll
            for (int k = 0; k < 8; ++k)
                o[k] = tb[nl * 67 + ((j * 8 + k) * 2 + bsel)];
            const int c = bn + nl - 1024, h = c >> 6, dd = c & 63;
            *(ushort8*)(vT + ((size_t)(bsel * HEADS + h) * DHEAD + dd) * T_SEQ + t0g + j * 8) = o;
        }
    }
}

// ---------------------------------------------------------------------------
// Output GEMM: ctx bf16 [4096,512] x w_out bf16 -> fp32 out.
// 64x64 tiles, grid (8,64) = 512 blocks, BK=64, dbuf. LDS 34,816 B.
// ---------------------------------------------------------------------------
__global__ __launch_bounds__(256)
void gemm_out(const unsigned short* __restrict__ A, const unsigned short* __restrict__ B,
              const float* __restrict__ bias, float* __restrict__ out)
{
    __shared__ unsigned short shmem[17408];
    const int bm  = blockIdx.y * 64;
    const int bn  = blockIdx.x * 64;
    const int tid = threadIdx.x;
    const int lane = tid & 63, w = tid >> 6;
    const int m16 = lane & 15, quad = lane >> 4;
    const int wm = (w & 1) * 32, wn = (w >> 1) * 32;
    const int srow = tid >> 2, scol = (tid & 3) * 16;

    floatx4 acc[2][2];
    #pragma unroll
    for (int i = 0; i < 2; ++i)
        #pragma unroll
        for (int j = 0; j < 2; ++j) acc[i][j] = (floatx4){0.f, 0.f, 0.f, 0.f};

    ushort8 ar[2], br[2];
    auto fetch = [&](int k0) {
        ar[0] = *(const ushort8*)(A + (size_t)(bm + srow) * 512 + k0 + scol);
        ar[1] = *(const ushort8*)(A + (size_t)(bm + srow) * 512 + k0 + scol + 8);
        br[0] = *(const ushort8*)(B + (size_t)(bn + srow) * 512 + k0 + scol);
        br[1] = *(const ushort8*)(B + (size_t)(bn + srow) * 512 + k0 + scol + 8);
    };
    auto store_stage = [&](int q) {
        unsigned short* As = shmem + q * 8704;
        unsigned short* Bs = shmem + q * 8704 + 4352;
        st8(&As[srow * 68 + scol + 0], ar[0]);
        st8(&As[srow * 68 + scol + 8], ar[1]);
        st8(&Bs[srow * 68 + scol + 0], br[0]);
        st8(&Bs[srow * 68 + scol + 8], br[1]);
    };

    fetch(0);
    store_stage(0);
    __syncthreads();

    for (int kt = 0; kt < 8; ++kt) {
        const int p = kt & 1;
        unsigned short* As = shmem + p * 8704;
        unsigned short* Bs = shmem + p * 8704 + 4352;
        if (kt + 1 < 8) fetch((kt + 1) * 64);
        #pragma unroll
        for (int ks = 0; ks < 2; ++ks) {
            short8 af[2], bf[2];
            #pragma unroll
            for (int f = 0; f < 2; ++f) {
                af[f] = ld_frag(&As[(wm + f * 16 + m16) * 68 + ks * 32 + quad * 8]);
                bf[f] = ld_frag(&Bs[(wn + f * 16 + m16) * 68 + ks * 32 + quad * 8]);
            }
            #pragma unroll
            for (int fm = 0; fm < 2; ++fm)
                #pragma unroll
                for (int fn = 0; fn < 2; ++fn)
                    acc[fm][fn] = MFMA16(af[fm], bf[fn], acc[fm][fn]);
        }
        if (kt + 1 < 8) store_stage(1 - p);
        __syncthreads();
    }

    #pragma unroll
    for (int fn = 0; fn < 2; ++fn) {
        const int n = bn + wn + fn * 16 + m16;
        const float bv = bias[n];
        #pragma unroll
        for (int fm = 0; fm < 2; ++fm)
            #pragma unroll
            for (int rgi = 0; rgi < 4; ++rgi) {
                const int m = bm + wm + fm * 16 + quad * 4 + rgi;
                out[(size_t)m * EMB + n] = acc[fm][fn][rgi] + bv;
            }
    }
}

// ---------------------------------------------------------------------------
// Fused MFMA attention — R1 proven version (89.8 us), barrier-reduced.
//   bd[t][s] = QR[t][T-1-t+s] (s<=t) | 0 (s==t+1) | QR[t+1][s-t-2] (s>=t+2)
// Wave-privacy facts (rows ibase+rgi = 16w+quad*4+rgi): ring rows and pbuf
// rows are wave-private -> no barrier between qr_half/ring adds, nor around
// the P round-trip. ONE barrier per s-tile at tile end. Diagonal Bd1-Bd3.
// LDS (u16): k@0 (2x4352) v@8704 (2x4352) rp@17408 (2x4352) pbuf@26112
// (4352) ring@30464 (64x133 = 8512). 77,952 B -> 2 blocks/CU.
// ---------------------------------------------------------------------------
__global__ __launch_bounds__(256)
void attn_mfma(const unsigned short* __restrict__ qg_, const unsigned short* __restrict__ kg_,
               const unsigned short* __restrict__ vtg_, const unsigned short* __restrict__ rg_,
               const float* __restrict__ rwb, const float* __restrict__ rrb,
               unsigned short* __restrict__ ctx)
{
    const int T   = T_SEQ;
    const int tb  = blockIdx.x;
    const int t0  = tb * 64;
    const int bh  = blockIdx.y;
    const int h   = bh & 7;
    const int b   = bh >> 3;
    const int tid = threadIdx.x;
    const int lane = tid & 63;
    const int w    = tid >> 6;
    const int m16  = lane & 15;
    const int quad = lane >> 4;
    const int ibase = 16 * w + quad * 4;

    __shared__ unsigned short lds[38976];
    unsigned short* pbuf  = lds + 26112;
    unsigned short* ring  = lds + 30464;
    unsigned short* qrw_s = lds;
    unsigned short* qrr_s = lds + 8704;

    const unsigned short* qg  = qg_  + ((size_t)bh * T + t0) * DHEAD;
    const unsigned short* kg  = kg_  + (size_t)bh * T * DHEAD;
    const unsigned short* vtg = vtg_ + (size_t)bh * DHEAD * T;
    const unsigned short* rg  = rg_  + h * DHEAD;

    const float QSCALE = 0.125f * 1.44269504089f;
    for (int idx = tid; idx < 65 * 16; idx += 256) {
        const int row = idx >> 4, c = (idx & 15) << 2;
        ushort4v qv = {0, 0, 0, 0};
        if (t0 + row < T) qv = *(const ushort4v*)(qg + row * DHEAD + c);
        const float4 rr = *(const float4*)(rrb + h * DHEAD + c);
        qrr_s[row * 68 + c + 0] = f2b((b2f(qv[0]) + rr.x) * QSCALE);
        qrr_s[row * 68 + c + 1] = f2b((b2f(qv[1]) + rr.y) * QSCALE);
        qrr_s[row * 68 + c + 2] = f2b((b2f(qv[2]) + rr.z) * QSCALE);
        qrr_s[row * 68 + c + 3] = f2b((b2f(qv[3]) + rr.w) * QSCALE);
        if (row < 64) {
            const float4 rw = *(const float4*)(rwb + h * DHEAD + c);
            qrw_s[row * 68 + c + 0] = f2b((b2f(qv[0]) + rw.x) * QSCALE);
            qrw_s[row * 68 + c + 1] = f2b((b2f(qv[1]) + rw.y) * QSCALE);
            qrw_s[row * 68 + c + 2] = f2b((b2f(qv[2]) + rw.z) * QSCALE);
            qrw_s[row * 68 + c + 3] = f2b((b2f(qv[3]) + rw.w) * QSCALE);
        }
    }
    __syncthreads();

    short8 a_ac[2], a_qrl[2], a_qru[2];
    {
        const unsigned short* p0 = &qrw_s[(16 * w + m16) * 68 + quad * 8];
        a_ac[0]  = ld_frag(p0);  a_ac[1]  = ld_frag(p0 + 32);
        const unsigned short* p1 = &qrr_s[(16 * w + m16) * 68 + quad * 8];
        a_qrl[0] = ld_frag(p1);  a_qrl[1] = ld_frag(p1 + 32);
        const unsigned short* p2 = &qrr_s[(16 * w + 1 + m16) * 68 + quad * 8];
        a_qru[0] = ld_frag(p2);  a_qru[1] = ld_frag(p2 + 32);
    }

    const int srow0 = tid >> 3,          scol0 = (tid & 7) * 8;
    const int srow1 = (tid + 256) >> 3,  scol1 = (tid & 7) * 8;

    ushort8 kr[2], vr[2], rr8[2];
    auto prefetch = [&](int s0n) {
        const bool ln = (s0n <= t0);
        const int jb = (ln ? (s0n + T - t0 - 64) : (s0n - t0 - 65)) + 64;
        int j0 = jb + srow0; j0 = j0 < 0 ? 0 : (j0 > T - 1 ? T - 1 : j0);
        int j1 = jb + srow1; j1 = j1 < 0 ? 0 : (j1 > T - 1 ? T - 1 : j1);
        kr[0]  = *(const ushort8*)(kg + (size_t)(s0n + srow0) * DHEAD + scol0);
        kr[1]  = *(const ushort8*)(kg + (size_t)(s0n + srow1) * DHEAD + scol1);
        vr[0]  = *(const ushort8*)(vtg + (size_t)srow0 * T + s0n + scol0);
        vr[1]  = *(const ushort8*)(vtg + (size_t)srow1 * T + s0n + scol1);
        rr8[0] = *(const ushort8*)(rg + (size_t)j0 * EMB + scol0);
        rr8[1] = *(const ushort8*)(rg + (size_t)j1 * EMB + scol1);
    };
    auto store_bufs = [&](int q) {
        unsigned short* kb = lds + q * 4352;
        unsigned short* vb = lds + 8704 + q * 4352;
        unsigned short* rb = lds + 17408 + q * 4352;
        st8(&kb[srow0 * 68 + scol0], kr[0]);
        st8(&kb[srow1 * 68 + scol1], kr[1]);
        st8(&vb[srow0 * 68 + scol0], vr[0]);
        st8(&vb[srow1 * 68 + scol1], vr[1]);
        st8(&rb[srow0 * 68 + scol0], rr8[0]);
        st8(&rb[srow1 * 68 + scol1], rr8[1]);
    };
    auto stage_to = [&](unsigned short* dstb, int jbase) {
        #pragma unroll
        for (int idx = tid; idx < 512; idx += 256) {
            const int row = idx >> 3, c = (idx & 7) * 8;
            int j = jbase + row; j = j < 0 ? 0 : (j > T - 1 ? T - 1 : j);
            st8(&dstb[row * 68 + c], *(const ushort8*)(rg + (size_t)j * EMB + c));
        }
    };
    auto qr_half = [&](const unsigned short* rsb, const short8* aq, int slotbase) {
        #pragma unroll
        for (int cc = 0; cc < 4; ++cc) {
            floatx4 q4 = (floatx4){0.f, 0.f, 0.f, 0.f};
            #pragma unroll
            for (int ks = 0; ks < 2; ++ks) {
                short8 bfr = ld_frag(&rsb[(16 * cc + m16) * 68 + ks * 32 + quad * 8]);
                q4 = MFMA16(aq[ks], bfr, q4);
            }
            #pragma unroll
            for (int rgi = 0; rgi < 4; ++rgi)
                ring[(ibase + rgi) * 133 + slotbase + 16 * cc + m16] = f2bt(q4[rgi]);
        }
    };

    floatx4 O[4];
    float lrun[4];
    #pragma unroll
    for (int ct = 0; ct < 4; ++ct) O[ct] = (floatx4){0.f, 0.f, 0.f, 0.f};
    #pragma unroll
    for (int rgi = 0; rgi < 4; ++rgi) lrun[rgi] = 0.f;

    {
        stage_to(lds + 17408 + 4352, T - t0 - 64);
        prefetch(0);
        __syncthreads();
        qr_half(lds + 17408 + 4352, a_qrl, 0);
        store_bufs(0);
        __syncthreads();
    }

    for (int na = 0; na < T / 64; ++na) {
        const int s0 = na * 64;
        const int p = na & 1;
        unsigned short* kb = lds + p * 4352;
        unsigned short* vb = lds + 8704 + p * 4352;
        unsigned short* rp = lds + 17408 + p * 4352;
        const bool lower = (s0 <= t0);
        const int nph    = lower ? (s0 >> 6) : ((s0 - t0) >> 6);
        const int rbase  = (nph & 1) * 64;
        const int wbase  = 64 - rbase;
        const bool hasNext = (na + 1 < T / 64);

        floatx4 acf[4];
        __builtin_amdgcn_s_setprio(1);
        #pragma unroll
        for (int ct = 0; ct < 4; ++ct) {
            acf[ct] = (floatx4){0.f, 0.f, 0.f, 0.f};
            #pragma unroll
            for (int ks = 0; ks < 2; ++ks) {
                short8 bfr = ld_frag(&kb[(16 * ct + m16) * 68 + ks * 32 + quad * 8]);
                acf[ct] = MFMA16(a_ac[ks], bfr, acf[ct]);
            }
        }
        __builtin_amdgcn_s_setprio(0);
        if (hasNext) prefetch(s0 + 64);
        qr_half(rp, lower ? a_qrl : a_qru, wbase);
        // no barrier: ring rows are wave-private, DS ops in-order per wave

        if (s0 != t0) {
            #pragma unroll
            for (int ct = 0; ct < 4; ++ct) {
                #pragma unroll
                for (int rgi = 0; rgi < 4; ++rgi) {
                    const int i = ibase + rgi;
                    const int slot = ((63 - i + 16 * ct + m16) + rbase) & 127;
                    acf[ct][rgi] += b2f(ring[i * 133 + slot]);
                }
            }
            if (s0 == t0 + 64 && lane == 48 && w == 3)
                acf[0][3] -= b2f(ring[63 * 133 + (rbase & 127)]);
        } else {
            #pragma unroll
            for (int ct = 0; ct < 4; ++ct) {
                #pragma unroll
                for (int rgi = 0; rgi < 4; ++rgi) {
                    const int i = ibase + rgi, u = 16 * ct + m16;
                    if (u <= i) acf[ct][rgi] += b2f(ring[i * 133 + (((63 - i + u) + rbase) & 127)]);
                }
            }
            unsigned short* rpo = lds + 17408 + (1 - p) * 4352;
            __syncthreads();                   // Bd1
            stage_to(rpo, -1);
            __syncthreads();                   // Bd2
            qr_half(rpo, a_qru, 64);
            __syncthreads();                   // Bd3 (also guards store_bufs(1-p) below)
            #pragma unroll
            for (int ct = 0; ct < 4; ++ct) {
                #pragma unroll
                for (int rgi = 0; rgi < 4; ++rgi) {
                    const int i = ibase + rgi, u = 16 * ct + m16;
                    if (u >= i + 2) acf[ct][rgi] += b2f(ring[i * 133 + 63 - i + u]);
                }
            }
        }

        #pragma unroll
        for (int rgi = 0; rgi < 4; ++rgi) {
            #pragma unroll
            for (int ct = 0; ct < 4; ++ct) {
                const float pv = exp2f(acf[ct][rgi]);
                acf[ct][rgi] = pv;
                lrun[rgi] += pv;
            }
        }
        // P -> dedicated pbuf (same-wave cross-lane exchange, no barrier)
        #pragma unroll
        for (int ct = 0; ct < 4; ++ct)
            #pragma unroll
            for (int rgi = 0; rgi < 4; ++rgi)
                pbuf[(ibase + rgi) * 68 + 16 * ct + m16] = f2bt(acf[ct][rgi]);

        short8 ap[2];
        {
            const unsigned short* pp = &pbuf[(16 * w + m16) * 68 + quad * 8];
            ap[0] = ld_frag(pp); ap[1] = ld_frag(pp + 32);
        }
        __builtin_amdgcn_s_setprio(1);
        #pragma unroll
        for (int ct = 0; ct < 4; ++ct) {
            #pragma unroll
            for (int ks = 0; ks < 2; ++ks) {
                short8 bfr = ld_frag(&vb[(16 * ct + m16) * 68 + ks * 32 + quad * 8]);
                O[ct] = MFMA16(ap[ks], bfr, O[ct]);
            }
        }
        __builtin_amdgcn_s_setprio(0);
        if (hasNext) store_bufs(1 - p);
        __syncthreads();                       // single tile-boundary barrier
    }

    #pragma unroll
    for (int rgi = 0; rgi < 4; ++rgi) {
        float l = lrun[rgi];
        #pragma unroll
        for (int off = 1; off < 16; off <<= 1)
            l += __shfl_xor(l, off);
        const float inv = 1.f / l;
        const int t = t0 + ibase + rgi;
        #pragma unroll
        for (int ct = 0; ct < 4; ++ct)
            ctx[((size_t)t * BATCH + b) * EMB + h * DHEAD + 16 * ct + m16] = f2bt(O[ct][rgi] * inv);
    }
}

// ---------------------------------------------------------------------------
// Workspace (ushort offsets), 15,990,784 ush = 31.98 MB:
//   0 inb | 2097152 posb | 3145728 w_inb | 3932160 w_posb | 4194304 free |
//   6291456 w_outb | 6553600 q_s | 8650752 k_s | 10747904 vT | 12845056 r_b |
//   13893632 ctx_b
// ---------------------------------------------------------------------------
extern "C" void kernel_launch(void* const* d_in, const int* in_sizes, int n_in,
                              void* d_out, int out_size, void* d_ws, size_t ws_size,
                              hipStream_t stream)
{
    const float* input = (const float*)d_in[0];
    const float* pos   = (const float*)d_in[1];
    const float* w_in  = (const float*)d_in[2];
    const float* w_out = (const float*)d_in[3];
    const float* w_pos = (const float*)d_in[4];
    const float* b_in  = (const float*)d_in[5];
    const float* b_out = (const float*)d_in[6];
    const float* b_pos = (const float*)d_in[7];
    const float* rwb   = (const float*)d_in[8];
    const float* rrb   = (const float*)d_in[9];

    unsigned short* ws     = (unsigned short*)d_ws;
    unsigned short* inb    = ws;
    unsigned short* posb   = ws + 2097152;
    unsigned short* w_inb  = ws + 3145728;
    unsigned short* w_posb = ws + 3932160;
    unsigned short* w_outb = ws + 6291456;
    unsigned short* q_s    = ws + 6553600;
    unsigned short* k_s    = ws + 8650752;
    unsigned short* vT     = ws + 10747904;
    unsigned short* r_b    = ws + 12845056;
    unsigned short* ctx_b  = ws + 13893632;

    cvt_all<<<4352, 256, 0, stream>>>(input, pos, w_in, w_pos, w_out,
                                      inb, posb, w_inb, w_posb, w_outb);
    gemm_qkv_pos<<<896, 256, 0, stream>>>(inb, w_inb, b_in, posb, w_posb, b_pos,
                                          q_s, k_s, vT, r_b);
    attn_mfma<<<dim3(32, 16), 256, 0, stream>>>(q_s, k_s, vT, r_b, rwb, rrb, ctx_b);
    gemm_out<<<dim3(8, 64), 256, 0, stream>>>(ctx_b, w_outb, b_out, (float*)d_out);
}

// Round 9
// 184.835 us; speedup vs baseline: 1.1135x; 1.0333x over previous
//
#include <hip/hip_runtime.h>

#define T_SEQ 2048
#define BATCH 2
#define HEADS 8
#define DHEAD 64
#define EMB   512

typedef __attribute__((ext_vector_type(8))) short short8;
typedef __attribute__((ext_vector_type(4))) float floatx4;
typedef __attribute__((ext_vector_type(8))) unsigned short ushort8;
typedef __attribute__((ext_vector_type(4))) unsigned short ushort4v;

// RNE convert (cold paths)
__device__ __forceinline__ unsigned short f2b(float f) {
    union { float f; unsigned u; } v; v.f = f;
    unsigned r = v.u + 0x7fffu + ((v.u >> 16) & 1u);
    return (unsigned short)(r >> 16);
}
// 1-op truncating convert (hot paths)
__device__ __forceinline__ unsigned short f2bt(float f) {
    union { float f; unsigned u; } v; v.f = f;
    return (unsigned short)(v.u >> 16);
}
__device__ __forceinline__ float b2f(unsigned short s) {
    union { unsigned u; float f; } v; v.u = ((unsigned)s) << 16; return v.f;
}
__device__ __forceinline__ short8 ld_frag(const unsigned short* p) {
    ushort4v lo = *(const ushort4v*)p;
    ushort4v hi = *(const ushort4v*)(p + 4);
    short8 r;
    r[0] = lo[0]; r[1] = lo[1]; r[2] = lo[2]; r[3] = lo[3];
    r[4] = hi[0]; r[5] = hi[1]; r[6] = hi[2]; r[7] = hi[3];
    return r;
}
__device__ __forceinline__ void st8(unsigned short* p, ushort8 v) {
    ushort4v lo = { v[0], v[1], v[2], v[3] };
    ushort4v hi = { v[4], v[5], v[6], v[7] };
    *(ushort4v*)p = lo;
    *(ushort4v*)(p + 4) = hi;
}
// async global->LDS 16B: per-lane global src, wave-uniform LDS base + lane*16
__device__ __forceinline__ void gl16(const unsigned short* g, unsigned short* l) {
    __builtin_amdgcn_global_load_lds(
        (const __attribute__((address_space(1))) unsigned int*)g,
        (__attribute__((address_space(3))) unsigned int*)l, 16, 0, 0);
}
#define MFMA16(a, b, c) __builtin_amdgcn_mfma_f32_16x16x32_bf16(a, b, c, 0, 0, 0)

// ---------------------------------------------------------------------------
// One-shot fp32 -> bf16 conversion of all 5 tensors. (R7 showed folding this
// into the GEMMs doubles their global traffic and loses ~19us -- keep it.)
// ---------------------------------------------------------------------------
__global__ __launch_bounds__(256)
void cvt_all(const float* __restrict__ s0, const float* __restrict__ s1,
             const float* __restrict__ s2, const float* __restrict__ s3,
             const float* __restrict__ s4,
             unsigned short* __restrict__ d0, unsigned short* __restrict__ d1,
             unsigned short* __restrict__ d2, unsigned short* __restrict__ d3,
             unsigned short* __restrict__ d4)
{
    const int i = blockIdx.x * 256 + threadIdx.x;
    const float* s; unsigned short* d; int off;
    if      (i <  524288) { s = s0; d = d0; off = i; }
    else if (i <  786432) { s = s1; d = d1; off = i -  524288; }
    else if (i <  983040) { s = s2; d = d2; off = i -  786432; }
    else if (i < 1048576) { s = s3; d = d3; off = i -  983040; }
    else if (i < 1114112) { s = s4; d = d4; off = i - 1048576; }
    else return;
    const float4 v = ((const float4*)s)[off];
    ushort4v o = { f2b(v.x), f2b(v.y), f2b(v.z), f2b(v.w) };
    ((ushort4v*)d)[off] = o;
}

// ---------------------------------------------------------------------------
// Fused QKV + pos projection GEMM (448 blocks), 128x128 tiles, BK=64.
// R9: staging via global_load_lds width=16 (no VGPR round-trip; loads
// overlap the whole compute phase, drained by the existing barrier).
// LDS is LINEAR [128][64] per tile (gload_lds requires contiguous dest,
// m104); bank conflicts on ds_read fixed by XOR swizzle applied on BOTH
// sides (G21): source col pre-swizzled per-lane (col8 ^= row&7), frag read
// uses u = (ks*4+quad)^(row&7). 2 lanes/bank = free (m136).
// LDS: As0@0 Bs0@8192 As1@16384 Bs1@24576 = 32,768 ush = 65,536 B -> 2/CU.
// Per wave per tile: 4 gl16 (rows w*32..w*32+31, 8 rows/instr).
// Epilogues unchanged from R6 (q/k scatter, vT transpose via tb, pos).
// ---------------------------------------------------------------------------
__global__ __launch_bounds__(256)
void gemm_qkv_pos(const unsigned short* __restrict__ inb, const unsigned short* __restrict__ w_inb,
                  const float* __restrict__ b_in,
                  const unsigned short* __restrict__ posb, const unsigned short* __restrict__ w_posb,
                  const float* __restrict__ b_pos,
                  unsigned short* __restrict__ q_s, unsigned short* __restrict__ k_s,
                  unsigned short* __restrict__ vT, unsigned short* __restrict__ r_b)
{
    __shared__ unsigned short shmem[32768];
    unsigned short* tb = shmem;        // 128x131 transpose buf alias (post-loop only)

    const int id = blockIdx.x;
    const bool isPos = (id >= 384);
    const int bx = isPos ? ((id - 384) & 3) : (id % 12);
    const int by = isPos ? ((id - 384) >> 2) : (id / 12);
    const unsigned short* A = isPos ? posb : inb;
    const unsigned short* B = isPos ? w_posb : w_inb;
    const float* bias = isPos ? b_pos : b_in;

    const int bm  = by * 128;
    const int bn  = bx * 128;
    const int tid = threadIdx.x;
    const int lane = tid & 63, w = tid >> 6;
    const int m16 = lane & 15, quad = lane >> 4;
    const int wm = (w & 1) * 64, wn = (w >> 1) * 64;
    const int lrow = lane >> 3;        // 0..7 within 8-row chunk
    const int lcol8 = lane & 7;        // 8-elem (16B) col block

    floatx4 acc[4][4];
    #pragma unroll
    for (int i = 0; i < 4; ++i)
        #pragma unroll
        for (int j = 0; j < 4; ++j) acc[i][j] = (floatx4){0.f, 0.f, 0.f, 0.f};

    // stage tile k0 into buffer q: linear LDS, source col pre-swizzled
    auto stage = [&](int q, int k0) {
        unsigned short* Ad = shmem + q * 16384;
        unsigned short* Bd = Ad + 8192;
        #pragma unroll
        for (int i = 0; i < 4; ++i) {
            const int rb  = w * 32 + i * 8;          // wave-uniform row base
            const int row = rb + lrow;               // per-lane row
            const int sc  = ((lcol8 ^ (row & 7)) * 8);
            gl16(A + (size_t)(bm + row) * 512 + k0 + sc, Ad + rb * 64);
            gl16(B + (size_t)(bn + row) * 512 + k0 + sc, Bd + rb * 64);
        }
    };
    // swizzled fragment read from linear tile
    auto frag = [&](const unsigned short* Ts, int row, int ks) {
        const int u = (ks * 4 + quad) ^ (row & 7);
        return ld_frag(&Ts[row * 64 + u * 8]);
    };

    stage(0, 0);
    __syncthreads();                   // drains vmcnt -> buf0 ready

    for (int kt = 0; kt < 8; ++kt) {
        const int p = kt & 1;
        unsigned short* As = shmem + p * 16384;
        unsigned short* Bs = As + 8192;
        if (kt + 1 < 8) stage(1 - p, (kt + 1) * 64);   // async into other buf
        #pragma unroll
        for (int ks = 0; ks < 2; ++ks) {
            short8 af[4], bf[4];
            #pragma unroll
            for (int f = 0; f < 4; ++f) {
                af[f] = frag(As, wm + f * 16 + m16, ks);
                bf[f] = frag(Bs, wn + f * 16 + m16, ks);
            }
            #pragma unroll
            for (int fm = 0; fm < 4; ++fm)
                #pragma unroll
                for (int fn = 0; fn < 4; ++fn)
                    acc[fm][fn] = MFMA16(af[fm], bf[fn], acc[fm][fn]);
        }
        __syncthreads();               // drains gload_lds + all frag reads
    }

    if (isPos) {
        #pragma unroll
        for (int fn = 0; fn < 4; ++fn) {
            const int n = bn + wn + fn * 16 + m16;
            const float bv = bias[n];
            #pragma unroll
            for (int fm = 0; fm < 4; ++fm)
                #pragma unroll
                for (int rgi = 0; rgi < 4; ++rgi) {
                    const int m = bm + wm + fm * 16 + quad * 4 + rgi;
                    r_b[(size_t)m * EMB + n] = f2b(acc[fm][fn][rgi] + bv);
                }
        }
    } else if (bn < 1024) {
        #pragma unroll
        for (int fn = 0; fn < 4; ++fn) {
            const int n = bn + wn + fn * 16 + m16;
            const float bv = bias[n];
            const int reg = n >> 9, c = n & 511, h = c >> 6, dd = c & 63;
            unsigned short* dst = reg == 0 ? q_s : k_s;
            #pragma unroll
            for (int fm = 0; fm < 4; ++fm)
                #pragma unroll
                for (int rgi = 0; rgi < 4; ++rgi) {
                    const int m = bm + wm + fm * 16 + quad * 4 + rgi;
                    const int t = m >> 1, b = m & 1;
                    dst[((size_t)(b * HEADS + h) * T_SEQ + t) * DHEAD + dd] = f2b(acc[fm][fn][rgi] + bv);
                }
        }
    } else {
        // vT transpose via tb (aliases buffers -- safe after final barrier)
        #pragma unroll
        for (int fn = 0; fn < 4; ++fn) {
            const int nl = wn + fn * 16 + m16;
            const float bv = bias[bn + nl];
            #pragma unroll
            for (int fm = 0; fm < 4; ++fm)
                #pragma unroll
                for (int rgi = 0; rgi < 4; ++rgi) {
                    const int ml = wm + fm * 16 + quad * 4 + rgi;
                    tb[nl * 131 + ml] = f2b(acc[fm][fn][rgi] + bv);
                }
        }
        __syncthreads();
        const int t0g = bm >> 1;
        for (int s2 = tid; s2 < 2048; s2 += 256) {
            const int nl = s2 >> 4;
            const int bsel = (s2 >> 3) & 1;
            const int j = s2 & 7;
            ushort8 o;
            #pragma unroll
            for (int k = 0; k < 8; ++k)
                o[k] = tb[nl * 131 + ((j * 8 + k) * 2 + bsel)];
            const int c = bn + nl - 1024, h = c >> 6, dd = c & 63;
            *(ushort8*)(vT + ((size_t)(bsel * HEADS + h) * DHEAD + dd) * T_SEQ + t0g + j * 8) = o;
        }
    }
}

// ---------------------------------------------------------------------------
// Output GEMM: ctx bf16 [4096,512] x w_out bf16 -> fp32 out.
// 64x64 tiles, grid (8,64) = 512 blocks, BK=64, dbuf. LDS 34,816 B. (R6)
// ---------------------------------------------------------------------------
__global__ __launch_bounds__(256)
void gemm_out(const unsigned short* __restrict__ A, const unsigned short* __restrict__ B,
              const float* __restrict__ bias, float* __restrict__ out)
{
    __shared__ unsigned short shmem[17408];
    const int bm  = blockIdx.y * 64;
    const int bn  = blockIdx.x * 64;
    const int tid = threadIdx.x;
    const int lane = tid & 63, w = tid >> 6;
    const int m16 = lane & 15, quad = lane >> 4;
    const int wm = (w & 1) * 32, wn = (w >> 1) * 32;
    const int srow = tid >> 2, scol = (tid & 3) * 16;

    floatx4 acc[2][2];
    #pragma unroll
    for (int i = 0; i < 2; ++i)
        #pragma unroll
        for (int j = 0; j < 2; ++j) acc[i][j] = (floatx4){0.f, 0.f, 0.f, 0.f};

    ushort8 ar[2], br[2];
    auto fetch = [&](int k0) {
        ar[0] = *(const ushort8*)(A + (size_t)(bm + srow) * 512 + k0 + scol);
        ar[1] = *(const ushort8*)(A + (size_t)(bm + srow) * 512 + k0 + scol + 8);
        br[0] = *(const ushort8*)(B + (size_t)(bn + srow) * 512 + k0 + scol);
        br[1] = *(const ushort8*)(B + (size_t)(bn + srow) * 512 + k0 + scol + 8);
    };
    auto store_stage = [&](int q) {
        unsigned short* As = shmem + q * 8704;
        unsigned short* Bs = shmem + q * 8704 + 4352;
        st8(&As[srow * 68 + scol + 0], ar[0]);
        st8(&As[srow * 68 + scol + 8], ar[1]);
        st8(&Bs[srow * 68 + scol + 0], br[0]);
        st8(&Bs[srow * 68 + scol + 8], br[1]);
    };

    fetch(0);
    store_stage(0);
    __syncthreads();

    for (int kt = 0; kt < 8; ++kt) {
        const int p = kt & 1;
        unsigned short* As = shmem + p * 8704;
        unsigned short* Bs = shmem + p * 8704 + 4352;
        if (kt + 1 < 8) fetch((kt + 1) * 64);
        #pragma unroll
        for (int ks = 0; ks < 2; ++ks) {
            short8 af[2], bf[2];
            #pragma unroll
            for (int f = 0; f < 2; ++f) {
                af[f] = ld_frag(&As[(wm + f * 16 + m16) * 68 + ks * 32 + quad * 8]);
                bf[f] = ld_frag(&Bs[(wn + f * 16 + m16) * 68 + ks * 32 + quad * 8]);
            }
            #pragma unroll
            for (int fm = 0; fm < 2; ++fm)
                #pragma unroll
                for (int fn = 0; fn < 2; ++fn)
                    acc[fm][fn] = MFMA16(af[fm], bf[fn], acc[fm][fn]);
        }
        if (kt + 1 < 8) store_stage(1 - p);
        __syncthreads();
    }

    #pragma unroll
    for (int fn = 0; fn < 2; ++fn) {
        const int n = bn + wn + fn * 16 + m16;
        const float bv = bias[n];
        #pragma unroll
        for (int fm = 0; fm < 2; ++fm)
            #pragma unroll
            for (int rgi = 0; rgi < 4; ++rgi) {
                const int m = bm + wm + fm * 16 + quad * 4 + rgi;
                out[(size_t)m * EMB + n] = acc[fm][fn][rgi] + bv;
            }
    }
}

// ---------------------------------------------------------------------------
// Fused MFMA attention — R1 proven version (~90 us), barrier-reduced.
//   bd[t][s] = QR[t][T-1-t+s] (s<=t) | 0 (s==t+1) | QR[t+1][s-t-2] (s>=t+2)
// Wave-privacy facts (rows ibase+rgi = 16w+quad*4+rgi): ring rows and pbuf
// rows are wave-private -> no barrier between qr_half/ring adds, nor around
// the P round-trip. ONE barrier per s-tile at tile end. Diagonal Bd1-Bd3.
// LDS (u16): k@0 (2x4352) v@8704 (2x4352) rp@17408 (2x4352) pbuf@26112
// (4352) ring@30464 (64x133 = 8512). 77,952 B -> 2 blocks/CU.
// ---------------------------------------------------------------------------
__global__ __launch_bounds__(256)
void attn_mfma(const unsigned short* __restrict__ qg_, const unsigned short* __restrict__ kg_,
               const unsigned short* __restrict__ vtg_, const unsigned short* __restrict__ rg_,
               const float* __restrict__ rwb, const float* __restrict__ rrb,
               unsigned short* __restrict__ ctx)
{
    const int T   = T_SEQ;
    const int tb  = blockIdx.x;
    const int t0  = tb * 64;
    const int bh  = blockIdx.y;
    const int h   = bh & 7;
    const int b   = bh >> 3;
    const int tid = threadIdx.x;
    const int lane = tid & 63;
    const int w    = tid >> 6;
    const int m16  = lane & 15;
    const int quad = lane >> 4;
    const int ibase = 16 * w + quad * 4;

    __shared__ unsigned short lds[38976];
    unsigned short* pbuf  = lds + 26112;
    unsigned short* ring  = lds + 30464;
    unsigned short* qrw_s = lds;
    unsigned short* qrr_s = lds + 8704;

    const unsigned short* qg  = qg_  + ((size_t)bh * T + t0) * DHEAD;
    const unsigned short* kg  = kg_  + (size_t)bh * T * DHEAD;
    const unsigned short* vtg = vtg_ + (size_t)bh * DHEAD * T;
    const unsigned short* rg  = rg_  + h * DHEAD;

    const float QSCALE = 0.125f * 1.44269504089f;
    for (int idx = tid; idx < 65 * 16; idx += 256) {
        const int row = idx >> 4, c = (idx & 15) << 2;
        ushort4v qv = {0, 0, 0, 0};
        if (t0 + row < T) qv = *(const ushort4v*)(qg + row * DHEAD + c);
        const float4 rr = *(const float4*)(rrb + h * DHEAD + c);
        qrr_s[row * 68 + c + 0] = f2b((b2f(qv[0]) + rr.x) * QSCALE);
        qrr_s[row * 68 + c + 1] = f2b((b2f(qv[1]) + rr.y) * QSCALE);
        qrr_s[row * 68 + c + 2] = f2b((b2f(qv[2]) + rr.z) * QSCALE);
        qrr_s[row * 68 + c + 3] = f2b((b2f(qv[3]) + rr.w) * QSCALE);
        if (row < 64) {
            const float4 rw = *(const float4*)(rwb + h * DHEAD + c);
            qrw_s[row * 68 + c + 0] = f2b((b2f(qv[0]) + rw.x) * QSCALE);
            qrw_s[row * 68 + c + 1] = f2b((b2f(qv[1]) + rw.y) * QSCALE);
            qrw_s[row * 68 + c + 2] = f2b((b2f(qv[2]) + rw.z) * QSCALE);
            qrw_s[row * 68 + c + 3] = f2b((b2f(qv[3]) + rw.w) * QSCALE);
        }
    }
    __syncthreads();

    short8 a_ac[2], a_qrl[2], a_qru[2];
    {
        const unsigned short* p0 = &qrw_s[(16 * w + m16) * 68 + quad * 8];
        a_ac[0]  = ld_frag(p0);  a_ac[1]  = ld_frag(p0 + 32);
        const unsigned short* p1 = &qrr_s[(16 * w + m16) * 68 + quad * 8];
        a_qrl[0] = ld_frag(p1);  a_qrl[1] = ld_frag(p1 + 32);
        const unsigned short* p2 = &qrr_s[(16 * w + 1 + m16) * 68 + quad * 8];
        a_qru[0] = ld_frag(p2);  a_qru[1] = ld_frag(p2 + 32);
    }

    const int srow0 = tid >> 3,          scol0 = (tid & 7) * 8;
    const int srow1 = (tid + 256) >> 3,  scol1 = (tid & 7) * 8;

    ushort8 kr[2], vr[2], rr8[2];
    auto prefetch = [&](int s0n) {
        const bool ln = (s0n <= t0);
        const int jb = (ln ? (s0n + T - t0 - 64) : (s0n - t0 - 65)) + 64;
        int j0 = jb + srow0; j0 = j0 < 0 ? 0 : (j0 > T - 1 ? T - 1 : j0);
        int j1 = jb + srow1; j1 = j1 < 0 ? 0 : (j1 > T - 1 ? T - 1 : j1);
        kr[0]  = *(const ushort8*)(kg + (size_t)(s0n + srow0) * DHEAD + scol0);
        kr[1]  = *(const ushort8*)(kg + (size_t)(s0n + srow1) * DHEAD + scol1);
        vr[0]  = *(const ushort8*)(vtg + (size_t)srow0 * T + s0n + scol0);
        vr[1]  = *(const ushort8*)(vtg + (size_t)srow1 * T + s0n + scol1);
        rr8[0] = *(const ushort8*)(rg + (size_t)j0 * EMB + scol0);
        rr8[1] = *(const ushort8*)(rg + (size_t)j1 * EMB + scol1);
    };
    auto store_bufs = [&](int q) {
        unsigned short* kb = lds + q * 4352;
        unsigned short* vb = lds + 8704 + q * 4352;
        unsigned short* rb = lds + 17408 + q * 4352;
        st8(&kb[srow0 * 68 + scol0], kr[0]);
        st8(&kb[srow1 * 68 + scol1], kr[1]);
        st8(&vb[srow0 * 68 + scol0], vr[0]);
        st8(&vb[srow1 * 68 + scol1], vr[1]);
        st8(&rb[srow0 * 68 + scol0], rr8[0]);
        st8(&rb[srow1 * 68 + scol1], rr8[1]);
    };
    auto stage_to = [&](unsigned short* dstb, int jbase) {
        #pragma unroll
        for (int idx = tid; idx < 512; idx += 256) {
            const int row = idx >> 3, c = (idx & 7) * 8;
            int j = jbase + row; j = j < 0 ? 0 : (j > T - 1 ? T - 1 : j);
            st8(&dstb[row * 68 + c], *(const ushort8*)(rg + (size_t)j * EMB + c));
        }
    };
    auto qr_half = [&](const unsigned short* rsb, const short8* aq, int slotbase) {
        #pragma unroll
        for (int cc = 0; cc < 4; ++cc) {
            floatx4 q4 = (floatx4){0.f, 0.f, 0.f, 0.f};
            #pragma unroll
            for (int ks = 0; ks < 2; ++ks) {
                short8 bfr = ld_frag(&rsb[(16 * cc + m16) * 68 + ks * 32 + quad * 8]);
                q4 = MFMA16(aq[ks], bfr, q4);
            }
            #pragma unroll
            for (int rgi = 0; rgi < 4; ++rgi)
                ring[(ibase + rgi) * 133 + slotbase + 16 * cc + m16] = f2bt(q4[rgi]);
        }
    };

    floatx4 O[4];
    float lrun[4];
    #pragma unroll
    for (int ct = 0; ct < 4; ++ct) O[ct] = (floatx4){0.f, 0.f, 0.f, 0.f};
    #pragma unroll
    for (int rgi = 0; rgi < 4; ++rgi) lrun[rgi] = 0.f;

    {
        stage_to(lds + 17408 + 4352, T - t0 - 64);
        prefetch(0);
        __syncthreads();
        qr_half(lds + 17408 + 4352, a_qrl, 0);
        store_bufs(0);
        __syncthreads();
    }

    for (int na = 0; na < T / 64; ++na) {
        const int s0 = na * 64;
        const int p = na & 1;
        unsigned short* kb = lds + p * 4352;
        unsigned short* vb = lds + 8704 + p * 4352;
        unsigned short* rp = lds + 17408 + p * 4352;
        const bool lower = (s0 <= t0);
        const int nph    = lower ? (s0 >> 6) : ((s0 - t0) >> 6);
        const int rbase  = (nph & 1) * 64;
        const int wbase  = 64 - rbase;
        const bool hasNext = (na + 1 < T / 64);

        floatx4 acf[4];
        __builtin_amdgcn_s_setprio(1);
        #pragma unroll
        for (int ct = 0; ct < 4; ++ct) {
            acf[ct] = (floatx4){0.f, 0.f, 0.f, 0.f};
            #pragma unroll
            for (int ks = 0; ks < 2; ++ks) {
                short8 bfr = ld_frag(&kb[(16 * ct + m16) * 68 + ks * 32 + quad * 8]);
                acf[ct] = MFMA16(a_ac[ks], bfr, acf[ct]);
            }
        }
        __builtin_amdgcn_s_setprio(0);
        if (hasNext) prefetch(s0 + 64);
        qr_half(rp, lower ? a_qrl : a_qru, wbase);
        // no barrier: ring rows are wave-private, DS ops in-order per wave

        if (s0 != t0) {
            #pragma unroll
            for (int ct = 0; ct < 4; ++ct) {
                #pragma unroll
                for (int rgi = 0; rgi < 4; ++rgi) {
                    const int i = ibase + rgi;
                    const int slot = ((63 - i + 16 * ct + m16) + rbase) & 127;
                    acf[ct][rgi] += b2f(ring[i * 133 + slot]);
                }
            }
            if (s0 == t0 + 64 && lane == 48 && w == 3)
                acf[0][3] -= b2f(ring[63 * 133 + (rbase & 127)]);
        } else {
            #pragma unroll
            for (int ct = 0; ct < 4; ++ct) {
                #pragma unroll
                for (int rgi = 0; rgi < 4; ++rgi) {
                    const int i = ibase + rgi, u = 16 * ct + m16;
                    if (u <= i) acf[ct][rgi] += b2f(ring[i * 133 + (((63 - i + u) + rbase) & 127)]);
                }
            }
            unsigned short* rpo = lds + 17408 + (1 - p) * 4352;
            __syncthreads();                   // Bd1
            stage_to(rpo, -1);
            __syncthreads();                   // Bd2
            qr_half(rpo, a_qru, 64);
            __syncthreads();                   // Bd3 (also guards store_bufs(1-p) below)
            #pragma unroll
            for (int ct = 0; ct < 4; ++ct) {
                #pragma unroll
                for (int rgi = 0; rgi < 4; ++rgi) {
                    const int i = ibase + rgi, u = 16 * ct + m16;
                    if (u >= i + 2) acf[ct][rgi] += b2f(ring[i * 133 + 63 - i + u]);
                }
            }
        }

        #pragma unroll
        for (int rgi = 0; rgi < 4; ++rgi) {
            #pragma unroll
            for (int ct = 0; ct < 4; ++ct) {
                const float pv = exp2f(acf[ct][rgi]);
                acf[ct][rgi] = pv;
                lrun[rgi] += pv;
            }
        }
        // P -> dedicated pbuf (same-wave cross-lane exchange, no barrier)
        #pragma unroll
        for (int ct = 0; ct < 4; ++ct)
            #pragma unroll
            for (int rgi = 0; rgi < 4; ++rgi)
                pbuf[(ibase + rgi) * 68 + 16 * ct + m16] = f2bt(acf[ct][rgi]);

        short8 ap[2];
        {
            const unsigned short* pp = &pbuf[(16 * w + m16) * 68 + quad * 8];
            ap[0] = ld_frag(pp); ap[1] = ld_frag(pp + 32);
        }
        __builtin_amdgcn_s_setprio(1);
        #pragma unroll
        for (int ct = 0; ct < 4; ++ct) {
            #pragma unroll
            for (int ks = 0; ks < 2; ++ks) {
                short8 bfr = ld_frag(&vb[(16 * ct + m16) * 68 + ks * 32 + quad * 8]);
                O[ct] = MFMA16(ap[ks], bfr, O[ct]);
            }
        }
        __builtin_amdgcn_s_setprio(0);
        if (hasNext) store_bufs(1 - p);
        __syncthreads();                       // single tile-boundary barrier
    }

    #pragma unroll
    for (int rgi = 0; rgi < 4; ++rgi) {
        float l = lrun[rgi];
        #pragma unroll
        for (int off = 1; off < 16; off <<= 1)
            l += __shfl_xor(l, off);
        const float inv = 1.f / l;
        const int t = t0 + ibase + rgi;
        #pragma unroll
        for (int ct = 0; ct < 4; ++ct)
            ctx[((size_t)t * BATCH + b) * EMB + h * DHEAD + 16 * ct + m16] = f2bt(O[ct][rgi] * inv);
    }
}

// ---------------------------------------------------------------------------
// Workspace (ushort offsets), 15,990,784 ush = 31.98 MB:
//   0 inb | 2097152 posb | 3145728 w_inb | 3932160 w_posb | 4194304 free |
//   6291456 w_outb | 6553600 q_s | 8650752 k_s | 10747904 vT | 12845056 r_b |
//   13893632 ctx_b
// ---------------------------------------------------------------------------
extern "C" void kernel_launch(void* const* d_in, const int* in_sizes, int n_in,
                              void* d_out, int out_size, void* d_ws, size_t ws_size,
                              hipStream_t stream)
{
    const float* input = (const float*)d_in[0];
    const float* pos   = (const float*)d_in[1];
    const float* w_in  = (const float*)d_in[2];
    const float* w_out = (const float*)d_in[3];
    const float* w_pos = (const float*)d_in[4];
    const float* b_in  = (const float*)d_in[5];
    const float* b_out = (const float*)d_in[6];
    const float* b_pos = (const float*)d_in[7];
    const float* rwb   = (const float*)d_in[8];
    const float* rrb   = (const float*)d_in[9];

    unsigned short* ws     = (unsigned short*)d_ws;
    unsigned short* inb    = ws;
    unsigned short* posb   = ws + 2097152;
    unsigned short* w_inb  = ws + 3145728;
    unsigned short* w_posb = ws + 3932160;
    unsigned short* w_outb = ws + 6291456;
    unsigned short* q_s    = ws + 6553600;
    unsigned short* k_s    = ws + 8650752;
    unsigned short* vT     = ws + 10747904;
    unsigned short* r_b    = ws + 12845056;
    unsigned short* ctx_b  = ws + 13893632;

    cvt_all<<<4352, 256, 0, stream>>>(input, pos, w_in, w_pos, w_out,
                                      inb, posb, w_inb, w_posb, w_outb);
    gemm_qkv_pos<<<448, 256, 0, stream>>>(inb, w_inb, b_in, posb, w_posb, b_pos,
                                          q_s, k_s, vT, r_b);
    attn_mfma<<<dim3(32, 16), 256, 0, stream>>>(q_s, k_s, vT, r_b, rwb, rrb, ctx_b);
    gemm_out<<<dim3(8, 64), 256, 0, stream>>>(ctx_b, w_outb, b_out, (float*)d_out);
}

// Round 10
// 182.715 us; speedup vs baseline: 1.1264x; 1.0116x over previous
//
#include <hip/hip_runtime.h>

#define T_SEQ 2048
#define BATCH 2
#define HEADS 8
#define DHEAD 64
#define EMB   512

typedef __attribute__((ext_vector_type(8))) short short8;
typedef __attribute__((ext_vector_type(4))) float floatx4;
typedef __attribute__((ext_vector_type(8))) unsigned short ushort8;
typedef __attribute__((ext_vector_type(4))) unsigned short ushort4v;

// RNE convert (cold paths)
__device__ __forceinline__ unsigned short f2b(float f) {
    union { float f; unsigned u; } v; v.f = f;
    unsigned r = v.u + 0x7fffu + ((v.u >> 16) & 1u);
    return (unsigned short)(r >> 16);
}
// 1-op truncating convert (hot paths)
__device__ __forceinline__ unsigned short f2bt(float f) {
    union { float f; unsigned u; } v; v.f = f;
    return (unsigned short)(v.u >> 16);
}
__device__ __forceinline__ float b2f(unsigned short s) {
    union { unsigned u; float f; } v; v.u = ((unsigned)s) << 16; return v.f;
}
__device__ __forceinline__ short8 ld_frag(const unsigned short* p) {
    ushort4v lo = *(const ushort4v*)p;
    ushort4v hi = *(const ushort4v*)(p + 4);
    short8 r;
    r[0] = lo[0]; r[1] = lo[1]; r[2] = lo[2]; r[3] = lo[3];
    r[4] = hi[0]; r[5] = hi[1]; r[6] = hi[2]; r[7] = hi[3];
    return r;
}
__device__ __forceinline__ void st8(unsigned short* p, ushort8 v) {
    ushort4v lo = { v[0], v[1], v[2], v[3] };
    ushort4v hi = { v[4], v[5], v[6], v[7] };
    *(ushort4v*)p = lo;
    *(ushort4v*)(p + 4) = hi;
}
// async global->LDS 16B: per-lane global src, wave-uniform LDS base + lane*16
__device__ __forceinline__ void gl16(const unsigned short* g, unsigned short* l) {
    __builtin_amdgcn_global_load_lds(
        (const __attribute__((address_space(1))) unsigned int*)g,
        (__attribute__((address_space(3))) unsigned int*)l, 16, 0, 0);
}
#define MFMA16(a, b, c) __builtin_amdgcn_mfma_f32_16x16x32_bf16(a, b, c, 0, 0, 0)

// ---------------------------------------------------------------------------
// One-shot fp32 -> bf16 conversion of all 5 tensors. (R7: folding this into
// the GEMMs multiplies global traffic -- keep standalone.)
// ---------------------------------------------------------------------------
__global__ __launch_bounds__(256)
void cvt_all(const float* __restrict__ s0, const float* __restrict__ s1,
             const float* __restrict__ s2, const float* __restrict__ s3,
             const float* __restrict__ s4,
             unsigned short* __restrict__ d0, unsigned short* __restrict__ d1,
             unsigned short* __restrict__ d2, unsigned short* __restrict__ d3,
             unsigned short* __restrict__ d4)
{
    const int i = blockIdx.x * 256 + threadIdx.x;
    const float* s; unsigned short* d; int off;
    if      (i <  524288) { s = s0; d = d0; off = i; }
    else if (i <  786432) { s = s1; d = d1; off = i -  524288; }
    else if (i <  983040) { s = s2; d = d2; off = i -  786432; }
    else if (i < 1048576) { s = s3; d = d3; off = i -  983040; }
    else if (i < 1114112) { s = s4; d = d4; off = i - 1048576; }
    else return;
    const float4 v = ((const float4*)s)[off];
    ushort4v o = { f2b(v.x), f2b(v.y), f2b(v.z), f2b(v.w) };
    ((ushort4v*)d)[off] = o;
}

// ---------------------------------------------------------------------------
// Fused QKV + pos projection GEMM.
// R10 = R9's gload_lds staging + R8's 64x128 grid:
//   grid 64x12 (QKV) + 32x4 (pos) = 896 blocks; LDS dbuf 49,152 B ->
//   3 blocks/CU resident, 12 waves/CU (R9 had 1.75 blocks/CU).
// Staging: 6 gl16/wave/tile (A 2, B 4), async, drained by the per-iter
// barrier; with 3 co-resident blocks the drains overlap across blocks.
// LDS linear per tile (gload_lds dest must be contiguous, m104); XOR
// swizzle on BOTH sides (G21): source col8 ^= row&7, read u=(ks*4+quad)^
// (row&7). 4 waves 2Mx2N, wave out 32x64 = acc[2][4].
// Epilogues verbatim from R8 (passed): q/k scatter fm<2, vT via tb 128x67.
// LDS: buf0 A@0(4096) B@4096(8192) | buf1 @12288 = 24,576 ush = 49,152 B.
// ---------------------------------------------------------------------------
__global__ __launch_bounds__(256)
void gemm_qkv_pos(const unsigned short* __restrict__ inb, const unsigned short* __restrict__ w_inb,
                  const float* __restrict__ b_in,
                  const unsigned short* __restrict__ posb, const unsigned short* __restrict__ w_posb,
                  const float* __restrict__ b_pos,
                  unsigned short* __restrict__ q_s, unsigned short* __restrict__ k_s,
                  unsigned short* __restrict__ vT, unsigned short* __restrict__ r_b)
{
    __shared__ unsigned short shmem[24576];
    unsigned short* tb = shmem;        // 128x67 transpose buf alias (post-loop)

    const int id = blockIdx.x;
    const bool isPos = (id >= 768);
    const int bx = isPos ? ((id - 768) & 3) : (id % 12);
    const int by = isPos ? ((id - 768) >> 2) : (id / 12);
    const unsigned short* A = isPos ? posb : inb;
    const unsigned short* B = isPos ? w_posb : w_inb;
    const float* bias = isPos ? b_pos : b_in;

    const int bm  = by * 64;
    const int bn  = bx * 128;
    const int tid = threadIdx.x;
    const int lane = tid & 63, w = tid >> 6;
    const int m16 = lane & 15, quad = lane >> 4;
    const int wm = (w & 1) * 32, wn = (w >> 1) * 64;
    const int lrow = lane >> 3;        // 0..7 within 8-row chunk
    const int lcol8 = lane & 7;        // 16B col block

    floatx4 acc[2][4];
    #pragma unroll
    for (int i = 0; i < 2; ++i)
        #pragma unroll
        for (int j = 0; j < 4; ++j) acc[i][j] = (floatx4){0.f, 0.f, 0.f, 0.f};

    auto stage = [&](int q, int k0) {
        unsigned short* Ad = shmem + q * 12288;
        unsigned short* Bd = Ad + 4096;
        #pragma unroll
        for (int i = 0; i < 2; ++i) {              // A: 16 rows/wave
            const int rb  = w * 16 + i * 8;
            const int row = rb + lrow;
            const int sc  = ((lcol8 ^ (row & 7)) * 8);
            gl16(A + (size_t)(bm + row) * 512 + k0 + sc, Ad + rb * 64);
        }
        #pragma unroll
        for (int i = 0; i < 4; ++i) {              // B: 32 rows/wave
            const int rb  = w * 32 + i * 8;
            const int row = rb + lrow;
            const int sc  = ((lcol8 ^ (row & 7)) * 8);
            gl16(B + (size_t)(bn + row) * 512 + k0 + sc, Bd + rb * 64);
        }
    };
    auto frag = [&](const unsigned short* Ts, int row, int ks) {
        const int u = (ks * 4 + quad) ^ (row & 7);
        return ld_frag(&Ts[row * 64 + u * 8]);
    };

    stage(0, 0);
    __syncthreads();

    for (int kt = 0; kt < 8; ++kt) {
        const int p = kt & 1;
        unsigned short* As = shmem + p * 12288;
        unsigned short* Bs = As + 4096;
        if (kt + 1 < 8) stage(1 - p, (kt + 1) * 64);
        #pragma unroll
        for (int ks = 0; ks < 2; ++ks) {
            short8 af[2], bf[4];
            #pragma unroll
            for (int f = 0; f < 2; ++f)
                af[f] = frag(As, wm + f * 16 + m16, ks);
            #pragma unroll
            for (int f = 0; f < 4; ++f)
                bf[f] = frag(Bs, wn + f * 16 + m16, ks);
            #pragma unroll
            for (int fm = 0; fm < 2; ++fm)
                #pragma unroll
                for (int fn = 0; fn < 4; ++fn)
                    acc[fm][fn] = MFMA16(af[fm], bf[fn], acc[fm][fn]);
        }
        __syncthreads();
    }

    if (isPos) {
        #pragma unroll
        for (int fn = 0; fn < 4; ++fn) {
            const int n = bn + wn + fn * 16 + m16;
            const float bv = bias[n];
            #pragma unroll
            for (int fm = 0; fm < 2; ++fm)
                #pragma unroll
                for (int rgi = 0; rgi < 4; ++rgi) {
                    const int m = bm + wm + fm * 16 + quad * 4 + rgi;
                    r_b[(size_t)m * EMB + n] = f2b(acc[fm][fn][rgi] + bv);
                }
        }
    } else if (bn < 1024) {
        #pragma unroll
        for (int fn = 0; fn < 4; ++fn) {
            const int n = bn + wn + fn * 16 + m16;
            const float bv = bias[n];
            const int reg = n >> 9, c = n & 511, h = c >> 6, dd = c & 63;
            unsigned short* dst = reg == 0 ? q_s : k_s;
            #pragma unroll
            for (int fm = 0; fm < 2; ++fm)
                #pragma unroll
                for (int rgi = 0; rgi < 4; ++rgi) {
                    const int m = bm + wm + fm * 16 + quad * 4 + rgi;
                    const int t = m >> 1, b = m & 1;
                    dst[((size_t)(b * HEADS + h) * T_SEQ + t) * DHEAD + dd] = f2b(acc[fm][fn][rgi] + bv);
                }
        }
    } else {
        // vT transpose: tb 128x67 (aliases buffers -- dead after final barrier)
        #pragma unroll
        for (int fn = 0; fn < 4; ++fn) {
            const int nl = wn + fn * 16 + m16;
            const float bv = bias[bn + nl];
            #pragma unroll
            for (int fm = 0; fm < 2; ++fm)
                #pragma unroll
                for (int rgi = 0; rgi < 4; ++rgi) {
                    const int ml = wm + fm * 16 + quad * 4 + rgi;
                    tb[nl * 67 + ml] = f2b(acc[fm][fn][rgi] + bv);
                }
        }
        __syncthreads();
        const int t0g = bm >> 1;
        for (int s2 = tid; s2 < 1024; s2 += 256) {
            const int nl = s2 >> 3;            // [0,128)
            const int bsel = (s2 >> 2) & 1;
            const int j = s2 & 3;              // [0,4): 8 t-values each
            ushort8 o;
            #pragma unroll
            for (int k = 0; k < 8; ++k)
                o[k] = tb[nl * 67 + ((j * 8 + k) * 2 + bsel)];
            const int c = bn + nl - 1024, h = c >> 6, dd = c & 63;
            *(ushort8*)(vT + ((size_t)(bsel * HEADS + h) * DHEAD + dd) * T_SEQ + t0g + j * 8) = o;
        }
    }
}

// ---------------------------------------------------------------------------
// Output GEMM: ctx bf16 [4096,512] x w_out bf16 -> fp32 out.
// 64x64 tiles, grid (8,64) = 512 blocks, BK=64, dbuf.
// R10: staging via gload_lds (4 gl16/wave/tile), linear LDS + XOR swizzle.
// LDS: 2 x (A 4096 + B 4096) = 16,384 ush = 32,768 B.
// ---------------------------------------------------------------------------
__global__ __launch_bounds__(256)
void gemm_out(const unsigned short* __restrict__ A, const unsigned short* __restrict__ B,
              const float* __restrict__ bias, float* __restrict__ out)
{
    __shared__ unsigned short shmem[16384];
    const int bm  = blockIdx.y * 64;
    const int bn  = blockIdx.x * 64;
    const int tid = threadIdx.x;
    const int lane = tid & 63, w = tid >> 6;
    const int m16 = lane & 15, quad = lane >> 4;
    const int wm = (w & 1) * 32, wn = (w >> 1) * 32;
    const int lrow = lane >> 3;
    const int lcol8 = lane & 7;

    floatx4 acc[2][2];
    #pragma unroll
    for (int i = 0; i < 2; ++i)
        #pragma unroll
        for (int j = 0; j < 2; ++j) acc[i][j] = (floatx4){0.f, 0.f, 0.f, 0.f};

    auto stage = [&](int q, int k0) {
        unsigned short* Ad = shmem + q * 8192;
        unsigned short* Bd = Ad + 4096;
        #pragma unroll
        for (int i = 0; i < 2; ++i) {
            const int rb  = w * 16 + i * 8;
            const int row = rb + lrow;
            const int sc  = ((lcol8 ^ (row & 7)) * 8);
            gl16(A + (size_t)(bm + row) * 512 + k0 + sc, Ad + rb * 64);
            gl16(B + (size_t)(bn + row) * 512 + k0 + sc, Bd + rb * 64);
        }
    };
    auto frag = [&](const unsigned short* Ts, int row, int ks) {
        const int u = (ks * 4 + quad) ^ (row & 7);
        return ld_frag(&Ts[row * 64 + u * 8]);
    };

    stage(0, 0);
    __syncthreads();

    for (int kt = 0; kt < 8; ++kt) {
        const int p = kt & 1;
        unsigned short* As = shmem + p * 8192;
        unsigned short* Bs = As + 4096;
        if (kt + 1 < 8) stage(1 - p, (kt + 1) * 64);
        #pragma unroll
        for (int ks = 0; ks < 2; ++ks) {
            short8 af[2], bf[2];
            #pragma unroll
            for (int f = 0; f < 2; ++f) {
                af[f] = frag(As, wm + f * 16 + m16, ks);
                bf[f] = frag(Bs, wn + f * 16 + m16, ks);
            }
            #pragma unroll
            for (int fm = 0; fm < 2; ++fm)
                #pragma unroll
                for (int fn = 0; fn < 2; ++fn)
                    acc[fm][fn] = MFMA16(af[fm], bf[fn], acc[fm][fn]);
        }
        __syncthreads();
    }

    #pragma unroll
    for (int fn = 0; fn < 2; ++fn) {
        const int n = bn + wn + fn * 16 + m16;
        const float bv = bias[n];
        #pragma unroll
        for (int fm = 0; fm < 2; ++fm)
            #pragma unroll
            for (int rgi = 0; rgi < 4; ++rgi) {
                const int m = bm + wm + fm * 16 + quad * 4 + rgi;
                out[(size_t)m * EMB + n] = acc[fm][fn][rgi] + bv;
            }
    }
}

// ---------------------------------------------------------------------------
// Fused MFMA attention — R1 proven version (~90 us), barrier-reduced.
//   bd[t][s] = QR[t][T-1-t+s] (s<=t) | 0 (s==t+1) | QR[t+1][s-t-2] (s>=t+2)
// Wave-privacy facts (rows ibase+rgi = 16w+quad*4+rgi): ring rows and pbuf
// rows are wave-private -> no barrier between qr_half/ring adds, nor around
// the P round-trip. ONE barrier per s-tile at tile end. Diagonal Bd1-Bd3.
// LDS (u16): k@0 (2x4352) v@8704 (2x4352) rp@17408 (2x4352) pbuf@26112
// (4352) ring@30464 (64x133 = 8512). 77,952 B -> 2 blocks/CU.
// ---------------------------------------------------------------------------
__global__ __launch_bounds__(256)
void attn_mfma(const unsigned short* __restrict__ qg_, const unsigned short* __restrict__ kg_,
               const unsigned short* __restrict__ vtg_, const unsigned short* __restrict__ rg_,
               const float* __restrict__ rwb, const float* __restrict__ rrb,
               unsigned short* __restrict__ ctx)
{
    const int T   = T_SEQ;
    const int tb  = blockIdx.x;
    const int t0  = tb * 64;
    const int bh  = blockIdx.y;
    const int h   = bh & 7;
    const int b   = bh >> 3;
    const int tid = threadIdx.x;
    const int lane = tid & 63;
    const int w    = tid >> 6;
    const int m16  = lane & 15;
    const int quad = lane >> 4;
    const int ibase = 16 * w + quad * 4;

    __shared__ unsigned short lds[38976];
    unsigned short* pbuf  = lds + 26112;
    unsigned short* ring  = lds + 30464;
    unsigned short* qrw_s = lds;
    unsigned short* qrr_s = lds + 8704;

    const unsigned short* qg  = qg_  + ((size_t)bh * T + t0) * DHEAD;
    const unsigned short* kg  = kg_  + (size_t)bh * T * DHEAD;
    const unsigned short* vtg = vtg_ + (size_t)bh * DHEAD * T;
    const unsigned short* rg  = rg_  + h * DHEAD;

    const float QSCALE = 0.125f * 1.44269504089f;
    for (int idx = tid; idx < 65 * 16; idx += 256) {
        const int row = idx >> 4, c = (idx & 15) << 2;
        ushort4v qv = {0, 0, 0, 0};
        if (t0 + row < T) qv = *(const ushort4v*)(qg + row * DHEAD + c);
        const float4 rr = *(const float4*)(rrb + h * DHEAD + c);
        qrr_s[row * 68 + c + 0] = f2b((b2f(qv[0]) + rr.x) * QSCALE);
        qrr_s[row * 68 + c + 1] = f2b((b2f(qv[1]) + rr.y) * QSCALE);
        qrr_s[row * 68 + c + 2] = f2b((b2f(qv[2]) + rr.z) * QSCALE);
        qrr_s[row * 68 + c + 3] = f2b((b2f(qv[3]) + rr.w) * QSCALE);
        if (row < 64) {
            const float4 rw = *(const float4*)(rwb + h * DHEAD + c);
            qrw_s[row * 68 + c + 0] = f2b((b2f(qv[0]) + rw.x) * QSCALE);
            qrw_s[row * 68 + c + 1] = f2b((b2f(qv[1]) + rw.y) * QSCALE);
            qrw_s[row * 68 + c + 2] = f2b((b2f(qv[2]) + rw.z) * QSCALE);
            qrw_s[row * 68 + c + 3] = f2b((b2f(qv[3]) + rw.w) * QSCALE);
        }
    }
    __syncthreads();

    short8 a_ac[2], a_qrl[2], a_qru[2];
    {
        const unsigned short* p0 = &qrw_s[(16 * w + m16) * 68 + quad * 8];
        a_ac[0]  = ld_frag(p0);  a_ac[1]  = ld_frag(p0 + 32);
        const unsigned short* p1 = &qrr_s[(16 * w + m16) * 68 + quad * 8];
        a_qrl[0] = ld_frag(p1);  a_qrl[1] = ld_frag(p1 + 32);
        const unsigned short* p2 = &qrr_s[(16 * w + 1 + m16) * 68 + quad * 8];
        a_qru[0] = ld_frag(p2);  a_qru[1] = ld_frag(p2 + 32);
    }

    const int srow0 = tid >> 3,          scol0 = (tid & 7) * 8;
    const int srow1 = (tid + 256) >> 3,  scol1 = (tid & 7) * 8;

    ushort8 kr[2], vr[2], rr8[2];
    auto prefetch = [&](int s0n) {
        const bool ln = (s0n <= t0);
        const int jb = (ln ? (s0n + T - t0 - 64) : (s0n - t0 - 65)) + 64;
        int j0 = jb + srow0; j0 = j0 < 0 ? 0 : (j0 > T - 1 ? T - 1 : j0);
        int j1 = jb + srow1; j1 = j1 < 0 ? 0 : (j1 > T - 1 ? T - 1 : j1);
        kr[0]  = *(const ushort8*)(kg + (size_t)(s0n + srow0) * DHEAD + scol0);
        kr[1]  = *(const ushort8*)(kg + (size_t)(s0n + srow1) * DHEAD + scol1);
        vr[0]  = *(const ushort8*)(vtg + (size_t)srow0 * T + s0n + scol0);
        vr[1]  = *(const ushort8*)(vtg + (size_t)srow1 * T + s0n + scol1);
        rr8[0] = *(const ushort8*)(rg + (size_t)j0 * EMB + scol0);
        rr8[1] = *(const ushort8*)(rg + (size_t)j1 * EMB + scol1);
    };
    auto store_bufs = [&](int q) {
        unsigned short* kb = lds + q * 4352;
        unsigned short* vb = lds + 8704 + q * 4352;
        unsigned short* rb = lds + 17408 + q * 4352;
        st8(&kb[srow0 * 68 + scol0], kr[0]);
        st8(&kb[srow1 * 68 + scol1], kr[1]);
        st8(&vb[srow0 * 68 + scol0], vr[0]);
        st8(&vb[srow1 * 68 + scol1], vr[1]);
        st8(&rb[srow0 * 68 + scol0], rr8[0]);
        st8(&rb[srow1 * 68 + scol1], rr8[1]);
    };
    auto stage_to = [&](unsigned short* dstb, int jbase) {
        #pragma unroll
        for (int idx = tid; idx < 512; idx += 256) {
            const int row = idx >> 3, c = (idx & 7) * 8;
            int j = jbase + row; j = j < 0 ? 0 : (j > T - 1 ? T - 1 : j);
            st8(&dstb[row * 68 + c], *(const ushort8*)(rg + (size_t)j * EMB + c));
        }
    };
    auto qr_half = [&](const unsigned short* rsb, const short8* aq, int slotbase) {
        #pragma unroll
        for (int cc = 0; cc < 4; ++cc) {
            floatx4 q4 = (floatx4){0.f, 0.f, 0.f, 0.f};
            #pragma unroll
            for (int ks = 0; ks < 2; ++ks) {
                short8 bfr = ld_frag(&rsb[(16 * cc + m16) * 68 + ks * 32 + quad * 8]);
                q4 = MFMA16(aq[ks], bfr, q4);
            }
            #pragma unroll
            for (int rgi = 0; rgi < 4; ++rgi)
                ring[(ibase + rgi) * 133 + slotbase + 16 * cc + m16] = f2bt(q4[rgi]);
        }
    };

    floatx4 O[4];
    float lrun[4];
    #pragma unroll
    for (int ct = 0; ct < 4; ++ct) O[ct] = (floatx4){0.f, 0.f, 0.f, 0.f};
    #pragma unroll
    for (int rgi = 0; rgi < 4; ++rgi) lrun[rgi] = 0.f;

    {
        stage_to(lds + 17408 + 4352, T - t0 - 64);
        prefetch(0);
        __syncthreads();
        qr_half(lds + 17408 + 4352, a_qrl, 0);
        store_bufs(0);
        __syncthreads();
    }

    for (int na = 0; na < T / 64; ++na) {
        const int s0 = na * 64;
        const int p = na & 1;
        unsigned short* kb = lds + p * 4352;
        unsigned short* vb = lds + 8704 + p * 4352;
        unsigned short* rp = lds + 17408 + p * 4352;
        const bool lower = (s0 <= t0);
        const int nph    = lower ? (s0 >> 6) : ((s0 - t0) >> 6);
        const int rbase  = (nph & 1) * 64;
        const int wbase  = 64 - rbase;
        const bool hasNext = (na + 1 < T / 64);

        floatx4 acf[4];
        __builtin_amdgcn_s_setprio(1);
        #pragma unroll
        for (int ct = 0; ct < 4; ++ct) {
            acf[ct] = (floatx4){0.f, 0.f, 0.f, 0.f};
            #pragma unroll
            for (int ks = 0; ks < 2; ++ks) {
                short8 bfr = ld_frag(&kb[(16 * ct + m16) * 68 + ks * 32 + quad * 8]);
                acf[ct] = MFMA16(a_ac[ks], bfr, acf[ct]);
            }
        }
        __builtin_amdgcn_s_setprio(0);
        if (hasNext) prefetch(s0 + 64);
        qr_half(rp, lower ? a_qrl : a_qru, wbase);
        // no barrier: ring rows are wave-private, DS ops in-order per wave

        if (s0 != t0) {
            #pragma unroll
            for (int ct = 0; ct < 4; ++ct) {
                #pragma unroll
                for (int rgi = 0; rgi < 4; ++rgi) {
                    const int i = ibase + rgi;
                    const int slot = ((63 - i + 16 * ct + m16) + rbase) & 127;
                    acf[ct][rgi] += b2f(ring[i * 133 + slot]);
                }
            }
            if (s0 == t0 + 64 && lane == 48 && w == 3)
                acf[0][3] -= b2f(ring[63 * 133 + (rbase & 127)]);
        } else {
            #pragma unroll
            for (int ct = 0; ct < 4; ++ct) {
                #pragma unroll
                for (int rgi = 0; rgi < 4; ++rgi) {
                    const int i = ibase + rgi, u = 16 * ct + m16;
                    if (u <= i) acf[ct][rgi] += b2f(ring[i * 133 + (((63 - i + u) + rbase) & 127)]);
                }
            }
            unsigned short* rpo = lds + 17408 + (1 - p) * 4352;
            __syncthreads();                   // Bd1
            stage_to(rpo, -1);
            __syncthreads();                   // Bd2
            qr_half(rpo, a_qru, 64);
            __syncthreads();                   // Bd3 (also guards store_bufs(1-p) below)
            #pragma unroll
            for (int ct = 0; ct < 4; ++ct) {
                #pragma unroll
                for (int rgi = 0; rgi < 4; ++rgi) {
                    const int i = ibase + rgi, u = 16 * ct + m16;
                    if (u >= i + 2) acf[ct][rgi] += b2f(ring[i * 133 + 63 - i + u]);
                }
            }
        }

        #pragma unroll
        for (int rgi = 0; rgi < 4; ++rgi) {
            #pragma unroll
            for (int ct = 0; ct < 4; ++ct) {
                const float pv = exp2f(acf[ct][rgi]);
                acf[ct][rgi] = pv;
                lrun[rgi] += pv;
            }
        }
        // P -> dedicated pbuf (same-wave cross-lane exchange, no barrier)
        #pragma unroll
        for (int ct = 0; ct < 4; ++ct)
            #pragma unroll
            for (int rgi = 0; rgi < 4; ++rgi)
                pbuf[(ibase + rgi) * 68 + 16 * ct + m16] = f2bt(acf[ct][rgi]);

        short8 ap[2];
        {
            const unsigned short* pp = &pbuf[(16 * w + m16) * 68 + quad * 8];
            ap[0] = ld_frag(pp); ap[1] = ld_frag(pp + 32);
        }
        __builtin_amdgcn_s_setprio(1);
        #pragma unroll
        for (int ct = 0; ct < 4; ++ct) {
            #pragma unroll
            for (int ks = 0; ks < 2; ++ks) {
                short8 bfr = ld_frag(&vb[(16 * ct + m16) * 68 + ks * 32 + quad * 8]);
                O[ct] = MFMA16(ap[ks], bfr, O[ct]);
            }
        }
        __builtin_amdgcn_s_setprio(0);
        if (hasNext) store_bufs(1 - p);
        __syncthreads();                       // single tile-boundary barrier
    }

    #pragma unroll
    for (int rgi = 0; rgi < 4; ++rgi) {
        float l = lrun[rgi];
        #pragma unroll
        for (int off = 1; off < 16; off <<= 1)
            l += __shfl_xor(l, off);
        const float inv = 1.f / l;
        const int t = t0 + ibase + rgi;
        #pragma unroll
        for (int ct = 0; ct < 4; ++ct)
            ctx[((size_t)t * BATCH + b) * EMB + h * DHEAD + 16 * ct + m16] = f2bt(O[ct][rgi] * inv);
    }
}

// ---------------------------------------------------------------------------
// Workspace (ushort offsets), 15,990,784 ush = 31.98 MB:
//   0 inb | 2097152 posb | 3145728 w_inb | 3932160 w_posb | 4194304 free |
//   6291456 w_outb | 6553600 q_s | 8650752 k_s | 10747904 vT | 12845056 r_b |
//   13893632 ctx_b
// ---------------------------------------------------------------------------
extern "C" void kernel_launch(void* const* d_in, const int* in_sizes, int n_in,
                              void* d_out, int out_size, void* d_ws, size_t ws_size,
                              hipStream_t stream)
{
    const float* input = (const float*)d_in[0];
    const float* pos   = (const float*)d_in[1];
    const float* w_in  = (const float*)d_in[2];
    const float* w_out = (const float*)d_in[3];
    const float* w_pos = (const float*)d_in[4];
    const float* b_in  = (const float*)d_in[5];
    const float* b_out = (const float*)d_in[6];
    const float* b_pos = (const float*)d_in[7];
    const float* rwb   = (const float*)d_in[8];
    const float* rrb   = (const float*)d_in[9];

    unsigned short* ws     = (unsigned short*)d_ws;
    unsigned short* inb    = ws;
    unsigned short* posb   = ws + 2097152;
    unsigned short* w_inb  = ws + 3145728;
    unsigned short* w_posb = ws + 3932160;
    unsigned short* w_outb = ws + 6291456;
    unsigned short* q_s    = ws + 6553600;
    unsigned short* k_s    = ws + 8650752;
    unsigned short* vT     = ws + 10747904;
    unsigned short* r_b    = ws + 12845056;
    unsigned short* ctx_b  = ws + 13893632;

    cvt_all<<<4352, 256, 0, stream>>>(input, pos, w_in, w_pos, w_out,
                                      inb, posb, w_inb, w_posb, w_outb);
    gemm_qkv_pos<<<896, 256, 0, stream>>>(inb, w_inb, b_in, posb, w_posb, b_pos,
                                          q_s, k_s, vT, r_b);
    attn_mfma<<<dim3(32, 16), 256, 0, stream>>>(q_s, k_s, vT, r_b, rwb, rrb, ctx_b);
    gemm_out<<<dim3(8, 64), 256, 0, stream>>>(ctx_b, w_outb, b_out, (float*)d_out);
}